// Round 2
// baseline (692.744 us; speedup 1.0000x reference)
//
#include <hip/hip_runtime.h>

typedef unsigned short u16;
typedef unsigned int   u32;
typedef __bf16 bf16x8 __attribute__((ext_vector_type(8)));
typedef float  f32x4  __attribute__((ext_vector_type(4)));

#define NF1 768   // input feature dim
#define NF2 256   // hidden feature dim

__device__ __forceinline__ u16 f2bf(float f) {
  u32 u = __builtin_bit_cast(u32, f);
  u += 0x7fffu + ((u >> 16) & 1u);      // RTNE
  return (u16)(u >> 16);
}
__device__ __forceinline__ float bf2f(u16 h) {
  return __builtin_bit_cast(float, ((u32)h) << 16);
}
__device__ __forceinline__ u32 pack2(float a, float b) {
  return (u32)f2bf(a) | ((u32)f2bf(b) << 16);
}

// ---------------- utility ----------------
__global__ void k_zero(u32* __restrict__ p, int n) {
  int i = blockIdx.x * 256 + threadIdx.x;
  if (i < n) p[i] = 0u;
}

// W1 [768,256] f32 row-major -> W1T [256,768] bf16
__global__ void k_w1t(const float* __restrict__ W1, u16* __restrict__ W1T) {
  int idx = blockIdx.x * 256 + threadIdx.x;
  if (idx < NF1 * NF2) {
    int k = idx >> 8, j = idx & 255;
    W1T[(size_t)j * NF1 + k] = f2bf(W1[idx]);
  }
}

// ---------------- GEMM1: H1 = bf16(x @ W1), [M,256] bf16 ----------------
// reg-prefetch pipeline: issue loads for tile kt+1 before computing tile kt,
// ds_write after the post-compute barrier (T14 async-STAGE split).
__global__ __launch_bounds__(256) void k_gemm(const float* __restrict__ X,
                                              const u16* __restrict__ W1T,
                                              u16* __restrict__ H1, int M) {
  __shared__ u16 lsA[128 * 64];
  __shared__ u16 lsB[128 * 64];   // B^T: [col][k]
  const int t    = threadIdx.x;
  const int m0   = blockIdx.x * 128;
  const int n0   = blockIdx.y * 128;
  const int lane = t & 63;
  const int wid  = t >> 6;
  const int wr   = wid >> 1, wc = wid & 1;
  const int r    = t >> 1;          // staging row (A) / col (B^T)
  const int h    = t & 1;           // k-half
  const int xrow = m0 + r;
  const bool arow_ok = (xrow < M);
  const float* xp = X + (size_t)xrow * NF1 + h * 32;
  const uint4* bp0 = (const uint4*)(W1T + (size_t)(n0 + r) * NF1) + h * 4;
  const int wbase = r * 64;
  const int swz   = (r & 7) << 3;   // XOR swizzle in u16 units (16B chunks)

  f32x4 acc[4][4];
  #pragma unroll
  for (int m = 0; m < 4; ++m)
    #pragma unroll
    for (int n = 0; n < 4; ++n) { f32x4 z = {0.f, 0.f, 0.f, 0.f}; acc[m][n] = z; }

  float4 pa[8];
  uint4  pb[4];

  auto issue = [&](int kt) {
    if (arow_ok) {
      const float4* p4 = (const float4*)(xp + kt * 64);
      #pragma unroll
      for (int c = 0; c < 8; ++c) pa[c] = p4[c];
    } else {
      #pragma unroll
      for (int c = 0; c < 8; ++c) pa[c] = make_float4(0.f, 0.f, 0.f, 0.f);
    }
    const uint4* p = bp0 + kt * 8;
    #pragma unroll
    for (int c = 0; c < 4; ++c) pb[c] = p[c];
  };
  auto commit = [&]() {
    #pragma unroll
    for (int c = 0; c < 4; ++c) {
      float4 v0 = pa[2 * c], v1 = pa[2 * c + 1];
      uint4 wv;
      wv.x = pack2(v0.x, v0.y);
      wv.y = pack2(v0.z, v0.w);
      wv.z = pack2(v1.x, v1.y);
      wv.w = pack2(v1.z, v1.w);
      int idx = wbase + ((h * 32 + c * 8) ^ swz);
      *(uint4*)(&lsA[idx]) = wv;
      *(uint4*)(&lsB[idx]) = pb[c];
    }
  };

  issue(0);
  commit();
  __syncthreads();

  for (int kt = 0; kt < NF1 / 64; ++kt) {
    if (kt + 1 < NF1 / 64) issue(kt + 1);   // prefetch next tile into regs
    #pragma unroll
    for (int ks = 0; ks < 2; ++ks) {
      bf16x8 af[4], bfr[4];
      const int ko = ks * 32 + (lane >> 4) * 8;
      #pragma unroll
      for (int m = 0; m < 4; ++m) {
        int row = wr * 64 + m * 16 + (lane & 15);
        af[m] = *(const bf16x8*)(&lsA[row * 64 + (ko ^ ((row & 7) << 3))]);
      }
      #pragma unroll
      for (int n = 0; n < 4; ++n) {
        int col = wc * 64 + n * 16 + (lane & 15);
        bfr[n] = *(const bf16x8*)(&lsB[col * 64 + (ko ^ ((col & 7) << 3))]);
      }
      #pragma unroll
      for (int m = 0; m < 4; ++m)
        #pragma unroll
        for (int n = 0; n < 4; ++n)
          acc[m][n] = __builtin_amdgcn_mfma_f32_16x16x32_bf16(af[m], bfr[n], acc[m][n], 0, 0, 0);
    }
    if (kt + 1 < NF1 / 64) {
      __syncthreads();   // all waves done reading LDS tile kt
      commit();          // pack + ds_write tile kt+1
      __syncthreads();   // tile kt+1 visible to all waves
    }
  }
  // epilogue: D col=lane&15, row=(lane>>4)*4+j  (m89-verified layout)
  #pragma unroll
  for (int m = 0; m < 4; ++m) {
    int rowb = m0 + wr * 64 + m * 16 + (lane >> 4) * 4;
    #pragma unroll
    for (int n = 0; n < 4; ++n) {
      int col = n0 + wc * 64 + n * 16 + (lane & 15);
      #pragma unroll
      for (int j = 0; j < 4; ++j) {
        int row = rowb + j;
        if (row < M) H1[(size_t)row * NF2 + col] = f2bf(acc[m][n][j]);
      }
    }
  }
}

// ---------------- degree / CSR build ----------------
__global__ void k_deg(const int* __restrict__ EI, int E, u32* __restrict__ deg) {
  int e = blockIdx.x * 256 + threadIdx.x;
  if (e < E) atomicAdd(&deg[EI[E + e]], 1u);
}

__global__ __launch_bounds__(1024) void k_scan1(const u32* __restrict__ deg,
                                                u32* __restrict__ rowptr,
                                                u32* __restrict__ bsum, int Nn) {
  __shared__ u32 sm[1024];
  int t = threadIdx.x;
  int i = blockIdx.x * 1024 + t;
  u32 v = (i < Nn) ? deg[i] : 0u;
  sm[t] = v;
  __syncthreads();
  #pragma unroll
  for (int off = 1; off < 1024; off <<= 1) {
    u32 x = (t >= off) ? sm[t - off] : 0u;
    __syncthreads();
    sm[t] += x;
    __syncthreads();
  }
  u32 incl = sm[t];
  if (i < Nn) rowptr[i] = incl - v;
  if (t == 1023) bsum[blockIdx.x] = incl;
}

__global__ void k_scan2(const u32* __restrict__ bsum, u32* __restrict__ boff, int nc) {
  __shared__ u32 sm[128];
  int t = threadIdx.x;
  u32 v = (t < nc) ? bsum[t] : 0u;
  sm[t] = v;
  __syncthreads();
  #pragma unroll
  for (int off = 1; off < 128; off <<= 1) {
    u32 x = (t >= off) ? sm[t - off] : 0u;
    __syncthreads();
    sm[t] += x;
    __syncthreads();
  }
  if (t < nc) boff[t] = sm[t] - v;
}

__global__ void k_scan3(u32* __restrict__ rowptr, const u32* __restrict__ boff,
                        u32* __restrict__ cursor, const u32* __restrict__ deg,
                        float* __restrict__ dinv, int Nn, int E) {
  int i = blockIdx.x * 256 + threadIdx.x;
  if (i < Nn) {
    u32 rp = rowptr[i] + boff[i >> 10];
    rowptr[i] = rp;
    cursor[i] = rp;
    dinv[i] = rsqrtf((float)deg[i] + 1.0f);
  }
  if (i == 0) rowptr[Nn] = (u32)E;
}

__global__ void k_fill(const int* __restrict__ EI, int E, int* __restrict__ cursor,
                       int* __restrict__ csr) {
  int e = blockIdx.x * 256 + threadIdx.x;
  if (e < E) {
    int s = EI[e], d = EI[E + e];
    int pos = atomicAdd(&cursor[d], 1);
    csr[pos] = s;
  }
}

// ---------------- fused: agg1 + self + b1 + relu + @W2 -> H2 [N,2] ----------------
__global__ __launch_bounds__(256) void k_agg1(const u16* __restrict__ H1,
                                              const int* __restrict__ csr,
                                              const u32* __restrict__ rowptr,
                                              const float* __restrict__ dinv,
                                              const float* __restrict__ B1,
                                              const float* __restrict__ W2,
                                              float* __restrict__ H2, int Nn) {
  int node = (blockIdx.x << 2) + (threadIdx.x >> 6);
  if (node >= Nn) return;
  int lane = threadIdx.x & 63;
  int rp0 = (int)rowptr[node], rp1 = (int)rowptr[node + 1];
  float dvi = dinv[node];
  float a0 = 0.f, a1 = 0.f, a2 = 0.f, a3 = 0.f;
  for (int e = rp0; e < rp1; e += 2) {
    int s0 = csr[e];
    bool has1 = (e + 1 < rp1);
    int s1 = has1 ? csr[e + 1] : s0;
    float n0 = dinv[s0] * dvi;
    float n1 = has1 ? dinv[s1] * dvi : 0.f;
    ushort4 v0 = ((const ushort4*)(H1 + (size_t)s0 * NF2))[lane];
    ushort4 v1 = ((const ushort4*)(H1 + (size_t)s1 * NF2))[lane];
    a0 += n0 * bf2f(v0.x) + n1 * bf2f(v1.x);
    a1 += n0 * bf2f(v0.y) + n1 * bf2f(v1.y);
    a2 += n0 * bf2f(v0.z) + n1 * bf2f(v1.z);
    a3 += n0 * bf2f(v0.w) + n1 * bf2f(v1.w);
  }
  {   // self-loop: norm = dinv^2 = 1/deg
    float ns = dvi * dvi;
    ushort4 v = ((const ushort4*)(H1 + (size_t)node * NF2))[lane];
    a0 += ns * bf2f(v.x);
    a1 += ns * bf2f(v.y);
    a2 += ns * bf2f(v.z);
    a3 += ns * bf2f(v.w);
  }
  float4 bb = ((const float4*)B1)[lane];
  float r0 = fmaxf(a0 + bb.x, 0.f);
  float r1 = fmaxf(a1 + bb.y, 0.f);
  float r2 = fmaxf(a2 + bb.z, 0.f);
  float r3 = fmaxf(a3 + bb.w, 0.f);
  float4 wA = ((const float4*)W2)[2 * lane];       // W2[4l..4l+1][0..1]
  float4 wB = ((const float4*)W2)[2 * lane + 1];   // W2[4l+2..4l+3][0..1]
  float p0 = r0 * wA.x + r1 * wA.z + r2 * wB.x + r3 * wB.z;
  float p1 = r0 * wA.y + r1 * wA.w + r2 * wB.y + r3 * wB.w;
  #pragma unroll
  for (int o = 32; o; o >>= 1) {
    p0 += __shfl_xor(p0, o);
    p1 += __shfl_xor(p1, o);
  }
  if (lane == 0) {
    H2[2 * (size_t)node]     = p0;
    H2[2 * (size_t)node + 1] = p1;
  }
}

// ---------------- layer-2 edge aggregation, pooled directly into graph bins ----------------
__global__ __launch_bounds__(256) void k_l2e(const int* __restrict__ EI, int E,
                                             const float* __restrict__ dinv,
                                             const float* __restrict__ H2,
                                             const int* __restrict__ batch,
                                             float* __restrict__ accg) {
  __shared__ float sb[1024];
  for (int i = threadIdx.x; i < 1024; i += 256) sb[i] = 0.f;
  __syncthreads();
  for (int e = blockIdx.x * 256 + threadIdx.x; e < E; e += gridDim.x * 256) {
    int s = EI[e], d = EI[E + e];
    float nrm = dinv[s] * dinv[d];
    float2 hv = *(const float2*)(H2 + 2 * (size_t)s);
    int g = batch[d];
    atomicAdd(&sb[2 * g],     nrm * hv.x);
    atomicAdd(&sb[2 * g + 1], nrm * hv.y);
  }
  __syncthreads();
  for (int i = threadIdx.x; i < 1024; i += 256)
    if (sb[i] != 0.f) atomicAdd(&accg[i], sb[i]);
}

// layer-2 self-loop + per-graph counts
__global__ __launch_bounds__(256) void k_l2n(int Nn, const float* __restrict__ dinv,
                                             const float* __restrict__ H2,
                                             const int* __restrict__ batch,
                                             float* __restrict__ accg,
                                             u32* __restrict__ gcnt) {
  __shared__ float sb[1024];
  __shared__ u32 sc[512];
  for (int i = threadIdx.x; i < 1024; i += 256) sb[i] = 0.f;
  for (int i = threadIdx.x; i < 512; i += 256) sc[i] = 0u;
  __syncthreads();
  for (int i = blockIdx.x * 256 + threadIdx.x; i < Nn; i += gridDim.x * 256) {
    int g = batch[i];
    float dv = dinv[i];
    float ns = dv * dv;
    float2 hv = *(const float2*)(H2 + 2 * (size_t)i);
    atomicAdd(&sb[2 * g],     ns * hv.x);
    atomicAdd(&sb[2 * g + 1], ns * hv.y);
    atomicAdd(&sc[g], 1u);
  }
  __syncthreads();
  for (int i = threadIdx.x; i < 1024; i += 256)
    if (sb[i] != 0.f) atomicAdd(&accg[i], sb[i]);
  for (int i = threadIdx.x; i < 512; i += 256)
    if (sc[i]) atomicAdd(&gcnt[i], sc[i]);
}

__global__ void k_final(const float* __restrict__ accg, const u32* __restrict__ gcnt,
                        const float* __restrict__ B2, float* __restrict__ out) {
  int i = blockIdx.x * 256 + threadIdx.x;
  if (i < 1024) {
    int g = i >> 1, c = i & 1;
    float cnt = (float)gcnt[g];
    float s = accg[i] + cnt * B2[c];
    out[i] = s / fmaxf(cnt, 1.0f);
  }
}

extern "C" void kernel_launch(void* const* d_in, const int* in_sizes, int n_in,
                              void* d_out, int out_size, void* d_ws, size_t ws_size,
                              hipStream_t stream) {
  const float* X     = (const float*)d_in[0];
  const int*   EI    = (const int*)d_in[1];
  const int*   BATCH = (const int*)d_in[2];
  const float* W1    = (const float*)d_in[3];
  const float* B1    = (const float*)d_in[4];
  const float* W2    = (const float*)d_in[5];
  const float* B2    = (const float*)d_in[6];
  const int Nn = in_sizes[0] / NF1;      // 100000
  const int E  = in_sizes[1] / 2;        // 1600000
  float* OUT = (float*)d_out;
  (void)n_in; (void)out_size; (void)ws_size;

  char* w = (char*)d_ws;
  size_t off = 0;
  auto alloc = [&](size_t bytes) -> void* {
    void* p = w + off;
    off = (off + bytes + 511) & ~(size_t)511;
    return p;
  };
  u32*   deg    = (u32*)alloc((size_t)Nn * 4);
  u32*   rowptr = (u32*)alloc(((size_t)Nn + 1) * 4);
  u32*   cursor = (u32*)alloc((size_t)Nn * 4);
  u32*   bsum   = (u32*)alloc(512);
  u32*   boff   = (u32*)alloc(512);
  float* dinv   = (float*)alloc((size_t)Nn * 4);
  int*   csr    = (int*)alloc((size_t)E * 4);
  u16*   H1     = (u16*)alloc((size_t)Nn * NF2 * 2);
  float* H2     = (float*)alloc((size_t)Nn * 2 * 4);
  float* accg   = (float*)alloc(1536 * 4);   // 1024 f32 sums + 512 u32 counts
  u32*   gcnt   = (u32*)(accg + 1024);
  u16*   W1T    = (u16*)alloc((size_t)NF1 * NF2 * 2);

  const int NC = (Nn + 1023) >> 10;          // scan chunks (98), must be <= 128

  hipLaunchKernelGGL(k_zero, dim3((Nn + 255) / 256), dim3(256), 0, stream, deg, Nn);
  hipLaunchKernelGGL(k_zero, dim3(6), dim3(256), 0, stream, (u32*)accg, 1536);
  hipLaunchKernelGGL(k_w1t, dim3((NF1 * NF2 + 255) / 256), dim3(256), 0, stream, W1, W1T);
  hipLaunchKernelGGL(k_gemm, dim3((Nn + 127) / 128, 2), dim3(256), 0, stream, X, W1T, H1, Nn);
  hipLaunchKernelGGL(k_deg, dim3((E + 255) / 256), dim3(256), 0, stream, EI, E, deg);
  hipLaunchKernelGGL(k_scan1, dim3(NC), dim3(1024), 0, stream, deg, rowptr, bsum, Nn);
  hipLaunchKernelGGL(k_scan2, dim3(1), dim3(128), 0, stream, bsum, boff, NC);
  hipLaunchKernelGGL(k_scan3, dim3((Nn + 255) / 256), dim3(256), 0, stream,
                     rowptr, boff, cursor, deg, dinv, Nn, E);
  hipLaunchKernelGGL(k_fill, dim3((E + 255) / 256), dim3(256), 0, stream,
                     EI, E, (int*)cursor, csr);
  hipLaunchKernelGGL(k_agg1, dim3((Nn + 3) / 4), dim3(256), 0, stream,
                     H1, csr, rowptr, dinv, B1, W2, H2, Nn);
  hipLaunchKernelGGL(k_l2e, dim3(512), dim3(256), 0, stream, EI, E, dinv, H2, BATCH, accg);
  hipLaunchKernelGGL(k_l2n, dim3(256), dim3(256), 0, stream, Nn, dinv, H2, BATCH, accg, gcnt);
  hipLaunchKernelGGL(k_final, dim3(4), dim3(256), 0, stream, accg, gcnt, B2, OUT);
}

// Round 3
// 687.289 us; speedup vs baseline: 1.0079x; 1.0079x over previous
//
#include <hip/hip_runtime.h>

typedef unsigned short u16;
typedef unsigned int   u32;
typedef __bf16 bf16x8 __attribute__((ext_vector_type(8)));
typedef float  f32x4  __attribute__((ext_vector_type(4)));

#define NF1 768   // input feature dim
#define NF2 256   // hidden feature dim

__device__ __forceinline__ u16 f2bf(float f) {
  u32 u = __builtin_bit_cast(u32, f);
  u += 0x7fffu + ((u >> 16) & 1u);      // RTNE
  return (u16)(u >> 16);
}
__device__ __forceinline__ float bf2f(u16 h) {
  return __builtin_bit_cast(float, ((u32)h) << 16);
}
__device__ __forceinline__ u32 pack2(float a, float b) {
  return (u32)f2bf(a) | ((u32)f2bf(b) << 16);
}

// ---------------- utility ----------------
__global__ void k_zero(u32* __restrict__ p, int n) {
  int i = blockIdx.x * 256 + threadIdx.x;
  if (i < n) p[i] = 0u;
}

// W1 [768,256] f32 row-major -> W1T [256,768] bf16
__global__ void k_w1t(const float* __restrict__ W1, u16* __restrict__ W1T) {
  int idx = blockIdx.x * 256 + threadIdx.x;
  if (idx < NF1 * NF2) {
    int k = idx >> 8, j = idx & 255;
    W1T[(size_t)j * NF1 + k] = f2bf(W1[idx]);
  }
}

// ---------------- GEMM1: H1 = bf16(x @ W1), [M,256] bf16 ----------------
// reg-prefetch pipeline; __launch_bounds__(256,1) so the prefetch registers
// (pa/pb ~48 VGPR) stay in VGPRs instead of spilling to scratch (R2 bug:
// 88-VGPR cap -> 216 MB scratch WRITE_SIZE).
__global__ __launch_bounds__(256, 1) void k_gemm(const float* __restrict__ X,
                                                 const u16* __restrict__ W1T,
                                                 u16* __restrict__ H1, int M) {
  __shared__ u16 lsA[128 * 64];
  __shared__ u16 lsB[128 * 64];   // B^T: [col][k]
  const int t    = threadIdx.x;
  const int m0   = blockIdx.x * 128;
  const int n0   = blockIdx.y * 128;
  const int lane = t & 63;
  const int wid  = t >> 6;
  const int wr   = wid >> 1, wc = wid & 1;
  const int r    = t >> 1;          // staging row (A) / col (B^T)
  const int h    = t & 1;           // k-half
  const int xrow = m0 + r;
  const bool arow_ok = (xrow < M);
  const float* xp = X + (size_t)xrow * NF1 + h * 32;
  const uint4* bp0 = (const uint4*)(W1T + (size_t)(n0 + r) * NF1) + h * 4;
  const int wbase = r * 64;
  const int swz   = (r & 7) << 3;   // XOR swizzle in u16 units (16B chunks)

  f32x4 acc[4][4];
  #pragma unroll
  for (int m = 0; m < 4; ++m)
    #pragma unroll
    for (int n = 0; n < 4; ++n) { f32x4 z = {0.f, 0.f, 0.f, 0.f}; acc[m][n] = z; }

  float4 pa[8];
  uint4  pb[4];

  auto issue = [&](int kt) {
    if (arow_ok) {
      const float4* p4 = (const float4*)(xp + kt * 64);
      #pragma unroll
      for (int c = 0; c < 8; ++c) pa[c] = p4[c];
    } else {
      #pragma unroll
      for (int c = 0; c < 8; ++c) pa[c] = make_float4(0.f, 0.f, 0.f, 0.f);
    }
    const uint4* p = bp0 + kt * 8;
    #pragma unroll
    for (int c = 0; c < 4; ++c) pb[c] = p[c];
  };
  auto commit = [&]() {
    #pragma unroll
    for (int c = 0; c < 4; ++c) {
      float4 v0 = pa[2 * c], v1 = pa[2 * c + 1];
      uint4 wv;
      wv.x = pack2(v0.x, v0.y);
      wv.y = pack2(v0.z, v0.w);
      wv.z = pack2(v1.x, v1.y);
      wv.w = pack2(v1.z, v1.w);
      int idx = wbase + ((h * 32 + c * 8) ^ swz);
      *(uint4*)(&lsA[idx]) = wv;
      *(uint4*)(&lsB[idx]) = pb[c];
    }
  };

  issue(0);
  commit();
  __syncthreads();

  for (int kt = 0; kt < NF1 / 64; ++kt) {
    if (kt + 1 < NF1 / 64) issue(kt + 1);   // prefetch next tile into regs
    #pragma unroll
    for (int ks = 0; ks < 2; ++ks) {
      bf16x8 af[4], bfr[4];
      const int ko = ks * 32 + (lane >> 4) * 8;
      #pragma unroll
      for (int m = 0; m < 4; ++m) {
        int row = wr * 64 + m * 16 + (lane & 15);
        af[m] = *(const bf16x8*)(&lsA[row * 64 + (ko ^ ((row & 7) << 3))]);
      }
      #pragma unroll
      for (int n = 0; n < 4; ++n) {
        int col = wc * 64 + n * 16 + (lane & 15);
        bfr[n] = *(const bf16x8*)(&lsB[col * 64 + (ko ^ ((col & 7) << 3))]);
      }
      #pragma unroll
      for (int m = 0; m < 4; ++m)
        #pragma unroll
        for (int n = 0; n < 4; ++n)
          acc[m][n] = __builtin_amdgcn_mfma_f32_16x16x32_bf16(af[m], bfr[n], acc[m][n], 0, 0, 0);
    }
    if (kt + 1 < NF1 / 64) {
      __syncthreads();   // all waves done reading LDS tile kt
      commit();          // pack + ds_write tile kt+1
      __syncthreads();   // tile kt+1 visible to all waves
    }
  }
  // epilogue: D col=lane&15, row=(lane>>4)*4+j  (m89-verified layout)
  #pragma unroll
  for (int m = 0; m < 4; ++m) {
    int rowb = m0 + wr * 64 + m * 16 + (lane >> 4) * 4;
    #pragma unroll
    for (int n = 0; n < 4; ++n) {
      int col = n0 + wc * 64 + n * 16 + (lane & 15);
      #pragma unroll
      for (int j = 0; j < 4; ++j) {
        int row = rowb + j;
        if (row < M) H1[(size_t)row * NF2 + col] = f2bf(acc[m][n][j]);
      }
    }
  }
}

// ---------------- degree / CSR build ----------------
__global__ void k_deg(const int* __restrict__ EI, int E, u32* __restrict__ deg) {
  int e = blockIdx.x * 256 + threadIdx.x;
  if (e < E) atomicAdd(&deg[EI[E + e]], 1u);
}

__global__ __launch_bounds__(1024) void k_scan1(const u32* __restrict__ deg,
                                                u32* __restrict__ rowptr,
                                                u32* __restrict__ bsum, int Nn) {
  __shared__ u32 sm[1024];
  int t = threadIdx.x;
  int i = blockIdx.x * 1024 + t;
  u32 v = (i < Nn) ? deg[i] : 0u;
  sm[t] = v;
  __syncthreads();
  #pragma unroll
  for (int off = 1; off < 1024; off <<= 1) {
    u32 x = (t >= off) ? sm[t - off] : 0u;
    __syncthreads();
    sm[t] += x;
    __syncthreads();
  }
  u32 incl = sm[t];
  if (i < Nn) rowptr[i] = incl - v;
  if (t == 1023) bsum[blockIdx.x] = incl;
}

__global__ void k_scan2(const u32* __restrict__ bsum, u32* __restrict__ boff, int nc) {
  __shared__ u32 sm[128];
  int t = threadIdx.x;
  u32 v = (t < nc) ? bsum[t] : 0u;
  sm[t] = v;
  __syncthreads();
  #pragma unroll
  for (int off = 1; off < 128; off <<= 1) {
    u32 x = (t >= off) ? sm[t - off] : 0u;
    __syncthreads();
    sm[t] += x;
    __syncthreads();
  }
  if (t < nc) boff[t] = sm[t] - v;
}

__global__ void k_scan3(u32* __restrict__ rowptr, const u32* __restrict__ boff,
                        u32* __restrict__ cursor, const u32* __restrict__ deg,
                        float* __restrict__ dinv, int Nn, int E) {
  int i = blockIdx.x * 256 + threadIdx.x;
  if (i < Nn) {
    u32 rp = rowptr[i] + boff[i >> 10];
    rowptr[i] = rp;
    cursor[i] = rp;
    dinv[i] = rsqrtf((float)deg[i] + 1.0f);
  }
  if (i == 0) rowptr[Nn] = (u32)E;
}

__global__ void k_fill(const int* __restrict__ EI, int E, int* __restrict__ cursor,
                       int* __restrict__ csr) {
  int e = blockIdx.x * 256 + threadIdx.x;
  if (e < E) {
    int s = EI[e], d = EI[E + e];
    int pos = atomicAdd(&cursor[d], 1);
    csr[pos] = s;
  }
}

// ---------------- fused: agg1 + self + b1 + relu + @W2 -> H2 [N,2] ----------------
__global__ __launch_bounds__(256) void k_agg1(const u16* __restrict__ H1,
                                              const int* __restrict__ csr,
                                              const u32* __restrict__ rowptr,
                                              const float* __restrict__ dinv,
                                              const float* __restrict__ B1,
                                              const float* __restrict__ W2,
                                              float* __restrict__ H2, int Nn) {
  int node = (blockIdx.x << 2) + (threadIdx.x >> 6);
  if (node >= Nn) return;
  int lane = threadIdx.x & 63;
  int rp0 = (int)rowptr[node], rp1 = (int)rowptr[node + 1];
  float dvi = dinv[node];
  float a0 = 0.f, a1 = 0.f, a2 = 0.f, a3 = 0.f;
  for (int e = rp0; e < rp1; e += 2) {
    int s0 = csr[e];
    bool has1 = (e + 1 < rp1);
    int s1 = has1 ? csr[e + 1] : s0;
    float n0 = dinv[s0] * dvi;
    float n1 = has1 ? dinv[s1] * dvi : 0.f;
    ushort4 v0 = ((const ushort4*)(H1 + (size_t)s0 * NF2))[lane];
    ushort4 v1 = ((const ushort4*)(H1 + (size_t)s1 * NF2))[lane];
    a0 += n0 * bf2f(v0.x) + n1 * bf2f(v1.x);
    a1 += n0 * bf2f(v0.y) + n1 * bf2f(v1.y);
    a2 += n0 * bf2f(v0.z) + n1 * bf2f(v1.z);
    a3 += n0 * bf2f(v0.w) + n1 * bf2f(v1.w);
  }
  {   // self-loop: norm = dinv^2 = 1/deg
    float ns = dvi * dvi;
    ushort4 v = ((const ushort4*)(H1 + (size_t)node * NF2))[lane];
    a0 += ns * bf2f(v.x);
    a1 += ns * bf2f(v.y);
    a2 += ns * bf2f(v.z);
    a3 += ns * bf2f(v.w);
  }
  float4 bb = ((const float4*)B1)[lane];
  float r0 = fmaxf(a0 + bb.x, 0.f);
  float r1 = fmaxf(a1 + bb.y, 0.f);
  float r2 = fmaxf(a2 + bb.z, 0.f);
  float r3 = fmaxf(a3 + bb.w, 0.f);
  float4 wA = ((const float4*)W2)[2 * lane];       // W2[4l..4l+1][0..1]
  float4 wB = ((const float4*)W2)[2 * lane + 1];   // W2[4l+2..4l+3][0..1]
  float p0 = r0 * wA.x + r1 * wA.z + r2 * wB.x + r3 * wB.z;
  float p1 = r0 * wA.y + r1 * wA.w + r2 * wB.y + r3 * wB.w;
  #pragma unroll
  for (int o = 32; o; o >>= 1) {
    p0 += __shfl_xor(p0, o);
    p1 += __shfl_xor(p1, o);
  }
  if (lane == 0) {
    H2[2 * (size_t)node]     = p0;
    H2[2 * (size_t)node + 1] = p1;
  }
}

// ---------------- layer-2 edge aggregation, pooled directly into graph bins ----------------
__global__ __launch_bounds__(256) void k_l2e(const int* __restrict__ EI, int E,
                                             const float* __restrict__ dinv,
                                             const float* __restrict__ H2,
                                             const int* __restrict__ batch,
                                             float* __restrict__ accg) {
  __shared__ float sb[1024];
  for (int i = threadIdx.x; i < 1024; i += 256) sb[i] = 0.f;
  __syncthreads();
  for (int e = blockIdx.x * 256 + threadIdx.x; e < E; e += gridDim.x * 256) {
    int s = EI[e], d = EI[E + e];
    float nrm = dinv[s] * dinv[d];
    float2 hv = *(const float2*)(H2 + 2 * (size_t)s);
    int g = batch[d];
    atomicAdd(&sb[2 * g],     nrm * hv.x);
    atomicAdd(&sb[2 * g + 1], nrm * hv.y);
  }
  __syncthreads();
  for (int i = threadIdx.x; i < 1024; i += 256)
    if (sb[i] != 0.f) atomicAdd(&accg[i], sb[i]);
}

// layer-2 self-loop + per-graph counts
__global__ __launch_bounds__(256) void k_l2n(int Nn, const float* __restrict__ dinv,
                                             const float* __restrict__ H2,
                                             const int* __restrict__ batch,
                                             float* __restrict__ accg,
                                             u32* __restrict__ gcnt) {
  __shared__ float sb[1024];
  __shared__ u32 sc[512];
  for (int i = threadIdx.x; i < 1024; i += 256) sb[i] = 0.f;
  for (int i = threadIdx.x; i < 512; i += 256) sc[i] = 0u;
  __syncthreads();
  for (int i = blockIdx.x * 256 + threadIdx.x; i < Nn; i += gridDim.x * 256) {
    int g = batch[i];
    float dv = dinv[i];
    float ns = dv * dv;
    float2 hv = *(const float2*)(H2 + 2 * (size_t)i);
    atomicAdd(&sb[2 * g],     ns * hv.x);
    atomicAdd(&sb[2 * g + 1], ns * hv.y);
    atomicAdd(&sc[g], 1u);
  }
  __syncthreads();
  for (int i = threadIdx.x; i < 1024; i += 256)
    if (sb[i] != 0.f) atomicAdd(&accg[i], sb[i]);
  for (int i = threadIdx.x; i < 512; i += 256)
    if (sc[i]) atomicAdd(&gcnt[i], sc[i]);
}

__global__ void k_final(const float* __restrict__ accg, const u32* __restrict__ gcnt,
                        const float* __restrict__ B2, float* __restrict__ out) {
  int i = blockIdx.x * 256 + threadIdx.x;
  if (i < 1024) {
    int g = i >> 1, c = i & 1;
    float cnt = (float)gcnt[g];
    float s = accg[i] + cnt * B2[c];
    out[i] = s / fmaxf(cnt, 1.0f);
  }
}

extern "C" void kernel_launch(void* const* d_in, const int* in_sizes, int n_in,
                              void* d_out, int out_size, void* d_ws, size_t ws_size,
                              hipStream_t stream) {
  const float* X     = (const float*)d_in[0];
  const int*   EI    = (const int*)d_in[1];
  const int*   BATCH = (const int*)d_in[2];
  const float* W1    = (const float*)d_in[3];
  const float* B1    = (const float*)d_in[4];
  const float* W2    = (const float*)d_in[5];
  const float* B2    = (const float*)d_in[6];
  const int Nn = in_sizes[0] / NF1;      // 100000
  const int E  = in_sizes[1] / 2;        // 1600000
  float* OUT = (float*)d_out;
  (void)n_in; (void)out_size; (void)ws_size;

  char* w = (char*)d_ws;
  size_t off = 0;
  auto alloc = [&](size_t bytes) -> void* {
    void* p = w + off;
    off = (off + bytes + 511) & ~(size_t)511;
    return p;
  };
  u32*   deg    = (u32*)alloc((size_t)Nn * 4);
  u32*   rowptr = (u32*)alloc(((size_t)Nn + 1) * 4);
  u32*   cursor = (u32*)alloc((size_t)Nn * 4);
  u32*   bsum   = (u32*)alloc(512);
  u32*   boff   = (u32*)alloc(512);
  float* dinv   = (float*)alloc((size_t)Nn * 4);
  int*   csr    = (int*)alloc((size_t)E * 4);
  u16*   H1     = (u16*)alloc((size_t)Nn * NF2 * 2);
  float* H2     = (float*)alloc((size_t)Nn * 2 * 4);
  float* accg   = (float*)alloc(1536 * 4);   // 1024 f32 sums + 512 u32 counts
  u32*   gcnt   = (u32*)(accg + 1024);
  u16*   W1T    = (u16*)alloc((size_t)NF1 * NF2 * 2);

  const int NC = (Nn + 1023) >> 10;          // scan chunks (98), must be <= 128

  hipLaunchKernelGGL(k_zero, dim3((Nn + 255) / 256), dim3(256), 0, stream, deg, Nn);
  hipLaunchKernelGGL(k_zero, dim3(6), dim3(256), 0, stream, (u32*)accg, 1536);
  hipLaunchKernelGGL(k_w1t, dim3((NF1 * NF2 + 255) / 256), dim3(256), 0, stream, W1, W1T);
  hipLaunchKernelGGL(k_gemm, dim3((Nn + 127) / 128, 2), dim3(256), 0, stream, X, W1T, H1, Nn);
  hipLaunchKernelGGL(k_deg, dim3((E + 255) / 256), dim3(256), 0, stream, EI, E, deg);
  hipLaunchKernelGGL(k_scan1, dim3(NC), dim3(1024), 0, stream, deg, rowptr, bsum, Nn);
  hipLaunchKernelGGL(k_scan2, dim3(1), dim3(128), 0, stream, bsum, boff, NC);
  hipLaunchKernelGGL(k_scan3, dim3((Nn + 255) / 256), dim3(256), 0, stream,
                     rowptr, boff, cursor, deg, dinv, Nn, E);
  hipLaunchKernelGGL(k_fill, dim3((E + 255) / 256), dim3(256), 0, stream,
                     EI, E, (int*)cursor, csr);
  hipLaunchKernelGGL(k_agg1, dim3((Nn + 3) / 4), dim3(256), 0, stream,
                     H1, csr, rowptr, dinv, B1, W2, H2, Nn);
  hipLaunchKernelGGL(k_l2e, dim3(512), dim3(256), 0, stream, EI, E, dinv, H2, BATCH, accg);
  hipLaunchKernelGGL(k_l2n, dim3(256), dim3(256), 0, stream, Nn, dinv, H2, BATCH, accg, gcnt);
  hipLaunchKernelGGL(k_final, dim3(4), dim3(256), 0, stream, accg, gcnt, B2, OUT);
}

// Round 4
// 595.706 us; speedup vs baseline: 1.1629x; 1.1537x over previous
//
#include <hip/hip_runtime.h>

typedef unsigned short u16;
typedef unsigned int   u32;
typedef __bf16 bf16x8 __attribute__((ext_vector_type(8)));
typedef float  f32x4  __attribute__((ext_vector_type(4)));

#define NF1 768   // input feature dim
#define NF2 256   // hidden feature dim

__device__ __forceinline__ u16 f2bf(float f) {
  u32 u = __builtin_bit_cast(u32, f);
  u += 0x7fffu + ((u >> 16) & 1u);      // RTNE
  return (u16)(u >> 16);
}
__device__ __forceinline__ float bf2f(u16 h) {
  return __builtin_bit_cast(float, ((u32)h) << 16);
}
__device__ __forceinline__ u32 pack2(float a, float b) {
  return (u32)f2bf(a) | ((u32)f2bf(b) << 16);
}

// ---------------- utility ----------------
__global__ void k_zero(u32* __restrict__ p, int n) {
  int i = blockIdx.x * 256 + threadIdx.x;
  if (i < n) p[i] = 0u;
}

// W1 [768,256] f32 row-major -> W1T [256,768] bf16
__global__ void k_w1t(const float* __restrict__ W1, u16* __restrict__ W1T) {
  int idx = blockIdx.x * 256 + threadIdx.x;
  if (idx < NF1 * NF2) {
    int k = idx >> 8, j = idx & 255;
    W1T[(size_t)j * NF1 + k] = f2bf(W1[idx]);
  }
}

// ---------------- GEMM1: H1 = bf16(x @ W1), [M,256] bf16 ----------------
// reg-prefetch pipeline with NAMED prefetch registers (no arrays, no lambdas):
// R2/R3 post-mortem: float4 pa[8]/uint4 pb[4] inside lambdas were kept as
// stack objects -> scratch (WRITE_SIZE 50->266 MB, rule #20). Named SSA
// values cannot be demoted to local memory.
__global__ __launch_bounds__(256, 1) void k_gemm(const float* __restrict__ X,
                                                 const u16* __restrict__ W1T,
                                                 u16* __restrict__ H1, int M) {
  __shared__ u16 lsA[128 * 64];
  __shared__ u16 lsB[128 * 64];   // B^T: [col][k]
  const int t    = threadIdx.x;
  const int m0   = blockIdx.x * 128;
  const int n0   = blockIdx.y * 128;
  const int lane = t & 63;
  const int wid  = t >> 6;
  const int wr   = wid >> 1, wc = wid & 1;
  const int r    = t >> 1;          // staging row (A) / col (B^T)
  const int h    = t & 1;           // k-half
  const int xrow = m0 + r;
  const bool arow_ok = (xrow < M);
  const float* xp = X + (size_t)xrow * NF1 + h * 32;
  const uint4* bp0 = (const uint4*)(W1T + (size_t)(n0 + r) * NF1) + h * 4;
  const int wbase = r * 64;
  const int swz   = (r & 7) << 3;   // XOR swizzle in u16 units (16B chunks)

  f32x4 acc[4][4];
  #pragma unroll
  for (int m = 0; m < 4; ++m)
    #pragma unroll
    for (int n = 0; n < 4; ++n) { f32x4 z = {0.f, 0.f, 0.f, 0.f}; acc[m][n] = z; }

  float4 a0, a1, a2, a3, a4, a5, a6, a7;   // named prefetch regs (A, f32)
  uint4  b0, b1, b2, b3;                   // named prefetch regs (B, bf16x8)

#define ISSUE(kt_) do {                                                        \
    if (arow_ok) {                                                             \
      const float4* p4_ = (const float4*)(xp + (kt_) * 64);                    \
      a0 = p4_[0]; a1 = p4_[1]; a2 = p4_[2]; a3 = p4_[3];                      \
      a4 = p4_[4]; a5 = p4_[5]; a6 = p4_[6]; a7 = p4_[7];                      \
    } else {                                                                   \
      a0 = a1 = a2 = a3 = a4 = a5 = a6 = a7 = make_float4(0.f, 0.f, 0.f, 0.f); \
    }                                                                          \
    const uint4* pB_ = bp0 + (kt_) * 8;                                        \
    b0 = pB_[0]; b1 = pB_[1]; b2 = pB_[2]; b3 = pB_[3];                        \
  } while (0)

#define PACK4(v0_, v1_) make_uint4(pack2((v0_).x, (v0_).y), pack2((v0_).z, (v0_).w), \
                                   pack2((v1_).x, (v1_).y), pack2((v1_).z, (v1_).w))

#define COMMIT() do {                                                          \
    *(uint4*)(&lsA[wbase + ((h * 32 + 0)  ^ swz)]) = PACK4(a0, a1);            \
    *(uint4*)(&lsA[wbase + ((h * 32 + 8)  ^ swz)]) = PACK4(a2, a3);            \
    *(uint4*)(&lsA[wbase + ((h * 32 + 16) ^ swz)]) = PACK4(a4, a5);            \
    *(uint4*)(&lsA[wbase + ((h * 32 + 24) ^ swz)]) = PACK4(a6, a7);            \
    *(uint4*)(&lsB[wbase + ((h * 32 + 0)  ^ swz)]) = b0;                       \
    *(uint4*)(&lsB[wbase + ((h * 32 + 8)  ^ swz)]) = b1;                       \
    *(uint4*)(&lsB[wbase + ((h * 32 + 16) ^ swz)]) = b2;                       \
    *(uint4*)(&lsB[wbase + ((h * 32 + 24) ^ swz)]) = b3;                       \
  } while (0)

  ISSUE(0);
  COMMIT();
  __syncthreads();

  for (int kt = 0; kt < NF1 / 64; ++kt) {
    if (kt + 1 < NF1 / 64) ISSUE(kt + 1);   // prefetch next tile into regs
    #pragma unroll
    for (int ks = 0; ks < 2; ++ks) {
      bf16x8 af[4], bfr[4];
      const int ko = ks * 32 + (lane >> 4) * 8;
      #pragma unroll
      for (int m = 0; m < 4; ++m) {
        int row = wr * 64 + m * 16 + (lane & 15);
        af[m] = *(const bf16x8*)(&lsA[row * 64 + (ko ^ ((row & 7) << 3))]);
      }
      #pragma unroll
      for (int n = 0; n < 4; ++n) {
        int col = wc * 64 + n * 16 + (lane & 15);
        bfr[n] = *(const bf16x8*)(&lsB[col * 64 + (ko ^ ((col & 7) << 3))]);
      }
      #pragma unroll
      for (int m = 0; m < 4; ++m)
        #pragma unroll
        for (int n = 0; n < 4; ++n)
          acc[m][n] = __builtin_amdgcn_mfma_f32_16x16x32_bf16(af[m], bfr[n], acc[m][n], 0, 0, 0);
    }
    if (kt + 1 < NF1 / 64) {
      __syncthreads();   // all waves done reading LDS tile kt
      COMMIT();          // pack + ds_write tile kt+1
      __syncthreads();   // tile kt+1 visible to all waves
    }
  }
#undef ISSUE
#undef PACK4
#undef COMMIT
  // epilogue: D col=lane&15, row=(lane>>4)*4+j  (m89-verified layout)
  #pragma unroll
  for (int m = 0; m < 4; ++m) {
    int rowb = m0 + wr * 64 + m * 16 + (lane >> 4) * 4;
    #pragma unroll
    for (int n = 0; n < 4; ++n) {
      int col = n0 + wc * 64 + n * 16 + (lane & 15);
      #pragma unroll
      for (int j = 0; j < 4; ++j) {
        int row = rowb + j;
        if (row < M) H1[(size_t)row * NF2 + col] = f2bf(acc[m][n][j]);
      }
    }
  }
}

// ---------------- degree / CSR build ----------------
__global__ void k_deg(const int* __restrict__ EI, int E, u32* __restrict__ deg) {
  int e = blockIdx.x * 256 + threadIdx.x;
  if (e < E) atomicAdd(&deg[EI[E + e]], 1u);
}

__global__ __launch_bounds__(1024) void k_scan1(const u32* __restrict__ deg,
                                                u32* __restrict__ rowptr,
                                                u32* __restrict__ bsum, int Nn) {
  __shared__ u32 sm[1024];
  int t = threadIdx.x;
  int i = blockIdx.x * 1024 + t;
  u32 v = (i < Nn) ? deg[i] : 0u;
  sm[t] = v;
  __syncthreads();
  #pragma unroll
  for (int off = 1; off < 1024; off <<= 1) {
    u32 x = (t >= off) ? sm[t - off] : 0u;
    __syncthreads();
    sm[t] += x;
    __syncthreads();
  }
  u32 incl = sm[t];
  if (i < Nn) rowptr[i] = incl - v;
  if (t == 1023) bsum[blockIdx.x] = incl;
}

__global__ void k_scan2(const u32* __restrict__ bsum, u32* __restrict__ boff, int nc) {
  __shared__ u32 sm[128];
  int t = threadIdx.x;
  u32 v = (t < nc) ? bsum[t] : 0u;
  sm[t] = v;
  __syncthreads();
  #pragma unroll
  for (int off = 1; off < 128; off <<= 1) {
    u32 x = (t >= off) ? sm[t - off] : 0u;
    __syncthreads();
    sm[t] += x;
    __syncthreads();
  }
  if (t < nc) boff[t] = sm[t] - v;
}

__global__ void k_scan3(u32* __restrict__ rowptr, const u32* __restrict__ boff,
                        u32* __restrict__ cursor, const u32* __restrict__ deg,
                        float* __restrict__ dinv, int Nn, int E) {
  int i = blockIdx.x * 256 + threadIdx.x;
  if (i < Nn) {
    u32 rp = rowptr[i] + boff[i >> 10];
    rowptr[i] = rp;
    cursor[i] = rp;
    dinv[i] = rsqrtf((float)deg[i] + 1.0f);
  }
  if (i == 0) rowptr[Nn] = (u32)E;
}

__global__ void k_fill(const int* __restrict__ EI, int E, int* __restrict__ cursor,
                       int* __restrict__ csr) {
  int e = blockIdx.x * 256 + threadIdx.x;
  if (e < E) {
    int s = EI[e], d = EI[E + e];
    int pos = atomicAdd(&cursor[d], 1);
    csr[pos] = s;
  }
}

// ---------------- fused: agg1 + self + b1 + relu + @W2 -> H2 [N,2] ----------------
__global__ __launch_bounds__(256) void k_agg1(const u16* __restrict__ H1,
                                              const int* __restrict__ csr,
                                              const u32* __restrict__ rowptr,
                                              const float* __restrict__ dinv,
                                              const float* __restrict__ B1,
                                              const float* __restrict__ W2,
                                              float* __restrict__ H2, int Nn) {
  int node = (blockIdx.x << 2) + (threadIdx.x >> 6);
  if (node >= Nn) return;
  int lane = threadIdx.x & 63;
  int rp0 = (int)rowptr[node], rp1 = (int)rowptr[node + 1];
  float dvi = dinv[node];
  float a0 = 0.f, a1 = 0.f, a2 = 0.f, a3 = 0.f;
  for (int e = rp0; e < rp1; e += 2) {
    int s0 = csr[e];
    bool has1 = (e + 1 < rp1);
    int s1 = has1 ? csr[e + 1] : s0;
    float n0 = dinv[s0] * dvi;
    float n1 = has1 ? dinv[s1] * dvi : 0.f;
    ushort4 v0 = ((const ushort4*)(H1 + (size_t)s0 * NF2))[lane];
    ushort4 v1 = ((const ushort4*)(H1 + (size_t)s1 * NF2))[lane];
    a0 += n0 * bf2f(v0.x) + n1 * bf2f(v1.x);
    a1 += n0 * bf2f(v0.y) + n1 * bf2f(v1.y);
    a2 += n0 * bf2f(v0.z) + n1 * bf2f(v1.z);
    a3 += n0 * bf2f(v0.w) + n1 * bf2f(v1.w);
  }
  {   // self-loop: norm = dinv^2 = 1/deg
    float ns = dvi * dvi;
    ushort4 v = ((const ushort4*)(H1 + (size_t)node * NF2))[lane];
    a0 += ns * bf2f(v.x);
    a1 += ns * bf2f(v.y);
    a2 += ns * bf2f(v.z);
    a3 += ns * bf2f(v.w);
  }
  float4 bb = ((const float4*)B1)[lane];
  float r0 = fmaxf(a0 + bb.x, 0.f);
  float r1 = fmaxf(a1 + bb.y, 0.f);
  float r2 = fmaxf(a2 + bb.z, 0.f);
  float r3 = fmaxf(a3 + bb.w, 0.f);
  float4 wA = ((const float4*)W2)[2 * lane];       // W2[4l..4l+1][0..1]
  float4 wB = ((const float4*)W2)[2 * lane + 1];   // W2[4l+2..4l+3][0..1]
  float p0 = r0 * wA.x + r1 * wA.z + r2 * wB.x + r3 * wB.z;
  float p1 = r0 * wA.y + r1 * wA.w + r2 * wB.y + r3 * wB.w;
  #pragma unroll
  for (int o = 32; o; o >>= 1) {
    p0 += __shfl_xor(p0, o);
    p1 += __shfl_xor(p1, o);
  }
  if (lane == 0) {
    H2[2 * (size_t)node]     = p0;
    H2[2 * (size_t)node + 1] = p1;
  }
}

// ---------------- layer-2 edge aggregation, pooled directly into graph bins ----------------
__global__ __launch_bounds__(256) void k_l2e(const int* __restrict__ EI, int E,
                                             const float* __restrict__ dinv,
                                             const float* __restrict__ H2,
                                             const int* __restrict__ batch,
                                             float* __restrict__ accg) {
  __shared__ float sb[1024];
  for (int i = threadIdx.x; i < 1024; i += 256) sb[i] = 0.f;
  __syncthreads();
  for (int e = blockIdx.x * 256 + threadIdx.x; e < E; e += gridDim.x * 256) {
    int s = EI[e], d = EI[E + e];
    float nrm = dinv[s] * dinv[d];
    float2 hv = *(const float2*)(H2 + 2 * (size_t)s);
    int g = batch[d];
    atomicAdd(&sb[2 * g],     nrm * hv.x);
    atomicAdd(&sb[2 * g + 1], nrm * hv.y);
  }
  __syncthreads();
  for (int i = threadIdx.x; i < 1024; i += 256)
    if (sb[i] != 0.f) atomicAdd(&accg[i], sb[i]);
}

// layer-2 self-loop + per-graph counts
__global__ __launch_bounds__(256) void k_l2n(int Nn, const float* __restrict__ dinv,
                                             const float* __restrict__ H2,
                                             const int* __restrict__ batch,
                                             float* __restrict__ accg,
                                             u32* __restrict__ gcnt) {
  __shared__ float sb[1024];
  __shared__ u32 sc[512];
  for (int i = threadIdx.x; i < 1024; i += 256) sb[i] = 0.f;
  for (int i = threadIdx.x; i < 512; i += 256) sc[i] = 0u;
  __syncthreads();
  for (int i = blockIdx.x * 256 + threadIdx.x; i < Nn; i += gridDim.x * 256) {
    int g = batch[i];
    float dv = dinv[i];
    float ns = dv * dv;
    float2 hv = *(const float2*)(H2 + 2 * (size_t)i);
    atomicAdd(&sb[2 * g],     ns * hv.x);
    atomicAdd(&sb[2 * g + 1], ns * hv.y);
    atomicAdd(&sc[g], 1u);
  }
  __syncthreads();
  for (int i = threadIdx.x; i < 1024; i += 256)
    if (sb[i] != 0.f) atomicAdd(&accg[i], sb[i]);
  for (int i = threadIdx.x; i < 512; i += 256)
    if (sc[i]) atomicAdd(&gcnt[i], sc[i]);
}

__global__ void k_final(const float* __restrict__ accg, const u32* __restrict__ gcnt,
                        const float* __restrict__ B2, float* __restrict__ out) {
  int i = blockIdx.x * 256 + threadIdx.x;
  if (i < 1024) {
    int g = i >> 1, c = i & 1;
    float cnt = (float)gcnt[g];
    float s = accg[i] + cnt * B2[c];
    out[i] = s / fmaxf(cnt, 1.0f);
  }
}

extern "C" void kernel_launch(void* const* d_in, const int* in_sizes, int n_in,
                              void* d_out, int out_size, void* d_ws, size_t ws_size,
                              hipStream_t stream) {
  const float* X     = (const float*)d_in[0];
  const int*   EI    = (const int*)d_in[1];
  const int*   BATCH = (const int*)d_in[2];
  const float* W1    = (const float*)d_in[3];
  const float* B1    = (const float*)d_in[4];
  const float* W2    = (const float*)d_in[5];
  const float* B2    = (const float*)d_in[6];
  const int Nn = in_sizes[0] / NF1;      // 100000
  const int E  = in_sizes[1] / 2;        // 1600000
  float* OUT = (float*)d_out;
  (void)n_in; (void)out_size; (void)ws_size;

  char* w = (char*)d_ws;
  size_t off = 0;
  auto alloc = [&](size_t bytes) -> void* {
    void* p = w + off;
    off = (off + bytes + 511) & ~(size_t)511;
    return p;
  };
  u32*   deg    = (u32*)alloc((size_t)Nn * 4);
  u32*   rowptr = (u32*)alloc(((size_t)Nn + 1) * 4);
  u32*   cursor = (u32*)alloc((size_t)Nn * 4);
  u32*   bsum   = (u32*)alloc(512);
  u32*   boff   = (u32*)alloc(512);
  float* dinv   = (float*)alloc((size_t)Nn * 4);
  int*   csr    = (int*)alloc((size_t)E * 4);
  u16*   H1     = (u16*)alloc((size_t)Nn * NF2 * 2);
  float* H2     = (float*)alloc((size_t)Nn * 2 * 4);
  float* accg   = (float*)alloc(1536 * 4);   // 1024 f32 sums + 512 u32 counts
  u32*   gcnt   = (u32*)(accg + 1024);
  u16*   W1T    = (u16*)alloc((size_t)NF1 * NF2 * 2);

  const int NC = (Nn + 1023) >> 10;          // scan chunks (98), must be <= 128

  hipLaunchKernelGGL(k_zero, dim3((Nn + 255) / 256), dim3(256), 0, stream, deg, Nn);
  hipLaunchKernelGGL(k_zero, dim3(6), dim3(256), 0, stream, (u32*)accg, 1536);
  hipLaunchKernelGGL(k_w1t, dim3((NF1 * NF2 + 255) / 256), dim3(256), 0, stream, W1, W1T);
  hipLaunchKernelGGL(k_gemm, dim3((Nn + 127) / 128, 2), dim3(256), 0, stream, X, W1T, H1, Nn);
  hipLaunchKernelGGL(k_deg, dim3((E + 255) / 256), dim3(256), 0, stream, EI, E, deg);
  hipLaunchKernelGGL(k_scan1, dim3(NC), dim3(1024), 0, stream, deg, rowptr, bsum, Nn);
  hipLaunchKernelGGL(k_scan2, dim3(1), dim3(128), 0, stream, bsum, boff, NC);
  hipLaunchKernelGGL(k_scan3, dim3((Nn + 255) / 256), dim3(256), 0, stream,
                     rowptr, boff, cursor, deg, dinv, Nn, E);
  hipLaunchKernelGGL(k_fill, dim3((E + 255) / 256), dim3(256), 0, stream,
                     EI, E, (int*)cursor, csr);
  hipLaunchKernelGGL(k_agg1, dim3((Nn + 3) / 4), dim3(256), 0, stream,
                     H1, csr, rowptr, dinv, B1, W2, H2, Nn);
  hipLaunchKernelGGL(k_l2e, dim3(512), dim3(256), 0, stream, EI, E, dinv, H2, BATCH, accg);
  hipLaunchKernelGGL(k_l2n, dim3(256), dim3(256), 0, stream, Nn, dinv, H2, BATCH, accg, gcnt);
  hipLaunchKernelGGL(k_final, dim3(4), dim3(256), 0, stream, accg, gcnt, B2, OUT);
}

// Round 5
// 585.944 us; speedup vs baseline: 1.1823x; 1.0167x over previous
//
#include <hip/hip_runtime.h>

typedef unsigned short u16;
typedef unsigned int   u32;
typedef __bf16 bf16x8 __attribute__((ext_vector_type(8)));
typedef float  f32x4  __attribute__((ext_vector_type(4)));

#define NF1 768   // input feature dim
#define NF2 256   // hidden feature dim

__device__ __forceinline__ u16 f2bf(float f) {
  u32 u = __builtin_bit_cast(u32, f);
  u += 0x7fffu + ((u >> 16) & 1u);      // RTNE
  return (u16)(u >> 16);
}
__device__ __forceinline__ float bf2f(u16 h) {
  return __builtin_bit_cast(float, ((u32)h) << 16);
}
__device__ __forceinline__ u32 pack2(float a, float b) {
  return (u32)f2bf(a) | ((u32)f2bf(b) << 16);
}

// ---------------- utility ----------------
__global__ void k_zero(u32* __restrict__ p, int n) {
  int i = blockIdx.x * 256 + threadIdx.x;
  if (i < n) p[i] = 0u;
}

// W1 [768,256] f32 row-major -> W1T [256,768] bf16
__global__ void k_w1t(const float* __restrict__ W1, u16* __restrict__ W1T) {
  int idx = blockIdx.x * 256 + threadIdx.x;
  if (idx < NF1 * NF2) {
    int k = idx >> 8, j = idx & 255;
    W1T[(size_t)j * NF1 + k] = f2bf(W1[idx]);
  }
}

// ---------------- GEMM1: H1 = bf16(x @ W1), [M,256] bf16 ----------------
// R5: double-buffered LDS + one barrier/iter. COMMIT(kt+1) waits on loads
// issued a FULL iteration earlier (latency covered by compute kt-1..kt);
// ISSUE(kt+2) keeps 12 loads in flight across the barrier (T3/T4 pattern:
// never drain vmcnt on the critical path). Named regs (R4) prevent scratch.
__global__ __launch_bounds__(256, 1) void k_gemm(const float* __restrict__ X,
                                                 const u16* __restrict__ W1T,
                                                 u16* __restrict__ H1, int M) {
  __shared__ u16 lsA[2][128 * 64];
  __shared__ u16 lsB[2][128 * 64];   // B^T: [col][k]
  const int t    = threadIdx.x;
  const int m0   = blockIdx.x * 128;
  const int n0   = blockIdx.y * 128;
  const int lane = t & 63;
  const int wid  = t >> 6;
  const int wr   = wid >> 1, wc = wid & 1;
  const int r    = t >> 1;          // staging row (A) / col (B^T)
  const int h    = t & 1;           // k-half
  const int xrow = m0 + r;
  const bool arow_ok = (xrow < M);
  const float* xp = X + (size_t)xrow * NF1 + h * 32;
  const uint4* bp0 = (const uint4*)(W1T + (size_t)(n0 + r) * NF1) + h * 4;
  const int wbase = r * 64;
  const int swz   = (r & 7) << 3;   // XOR swizzle in u16 units (16B chunks)

  f32x4 acc[4][4];
  #pragma unroll
  for (int m = 0; m < 4; ++m)
    #pragma unroll
    for (int n = 0; n < 4; ++n) { f32x4 z = {0.f, 0.f, 0.f, 0.f}; acc[m][n] = z; }

  float4 a0, a1, a2, a3, a4, a5, a6, a7;   // named prefetch regs (A, f32)
  uint4  b0, b1, b2, b3;                   // named prefetch regs (B, bf16x8)

#define ISSUE(kt_) do {                                                        \
    if (arow_ok) {                                                             \
      const float4* p4_ = (const float4*)(xp + (kt_) * 64);                    \
      a0 = p4_[0]; a1 = p4_[1]; a2 = p4_[2]; a3 = p4_[3];                      \
      a4 = p4_[4]; a5 = p4_[5]; a6 = p4_[6]; a7 = p4_[7];                      \
    } else {                                                                   \
      a0 = a1 = a2 = a3 = a4 = a5 = a6 = a7 = make_float4(0.f, 0.f, 0.f, 0.f); \
    }                                                                          \
    const uint4* pB_ = bp0 + (kt_) * 8;                                        \
    b0 = pB_[0]; b1 = pB_[1]; b2 = pB_[2]; b3 = pB_[3];                        \
  } while (0)

#define PACK4(v0_, v1_) make_uint4(pack2((v0_).x, (v0_).y), pack2((v0_).z, (v0_).w), \
                                   pack2((v1_).x, (v1_).y), pack2((v1_).z, (v1_).w))

#define COMMIT(buf_) do {                                                      \
    u16* LA_ = lsA[buf_];                                                      \
    u16* LB_ = lsB[buf_];                                                      \
    *(uint4*)(&LA_[wbase + ((h * 32 + 0)  ^ swz)]) = PACK4(a0, a1);            \
    *(uint4*)(&LA_[wbase + ((h * 32 + 8)  ^ swz)]) = PACK4(a2, a3);            \
    *(uint4*)(&LA_[wbase + ((h * 32 + 16) ^ swz)]) = PACK4(a4, a5);            \
    *(uint4*)(&LA_[wbase + ((h * 32 + 24) ^ swz)]) = PACK4(a6, a7);            \
    *(uint4*)(&LB_[wbase + ((h * 32 + 0)  ^ swz)]) = b0;                       \
    *(uint4*)(&LB_[wbase + ((h * 32 + 8)  ^ swz)]) = b1;                       \
    *(uint4*)(&LB_[wbase + ((h * 32 + 16) ^ swz)]) = b2;                       \
    *(uint4*)(&LB_[wbase + ((h * 32 + 24) ^ swz)]) = b3;                       \
  } while (0)

  ISSUE(0);
  COMMIT(0);        // prologue: immediate wait is fine (once)
  ISSUE(1);         // tile 1 loads in flight across the barrier
  __syncthreads();

  const int NT = NF1 / 64;   // 12
  for (int kt = 0; kt < NT; ++kt) {
    if (kt + 1 < NT) COMMIT((kt + 1) & 1);   // waits on loads issued LAST iter
    if (kt + 2 < NT) ISSUE(kt + 2);          // next loads go in flight
    const u16* curA = lsA[kt & 1];
    const u16* curB = lsB[kt & 1];
    #pragma unroll
    for (int ks = 0; ks < 2; ++ks) {
      bf16x8 af[4], bfr[4];
      const int ko = ks * 32 + (lane >> 4) * 8;
      #pragma unroll
      for (int m = 0; m < 4; ++m) {
        int row = wr * 64 + m * 16 + (lane & 15);
        af[m] = *(const bf16x8*)(&curA[row * 64 + (ko ^ ((row & 7) << 3))]);
      }
      #pragma unroll
      for (int n = 0; n < 4; ++n) {
        int col = wc * 64 + n * 16 + (lane & 15);
        bfr[n] = *(const bf16x8*)(&curB[col * 64 + (ko ^ ((col & 7) << 3))]);
      }
      #pragma unroll
      for (int m = 0; m < 4; ++m)
        #pragma unroll
        for (int n = 0; n < 4; ++n)
          acc[m][n] = __builtin_amdgcn_mfma_f32_16x16x32_bf16(af[m], bfr[n], acc[m][n], 0, 0, 0);
    }
    if (kt + 1 < NT) __syncthreads();   // buf[(kt+1)&1] committed by all waves
  }
#undef ISSUE
#undef PACK4
#undef COMMIT
  // epilogue: D col=lane&15, row=(lane>>4)*4+j  (m89-verified layout)
  #pragma unroll
  for (int m = 0; m < 4; ++m) {
    int rowb = m0 + wr * 64 + m * 16 + (lane >> 4) * 4;
    #pragma unroll
    for (int n = 0; n < 4; ++n) {
      int col = n0 + wc * 64 + n * 16 + (lane & 15);
      #pragma unroll
      for (int j = 0; j < 4; ++j) {
        int row = rowb + j;
        if (row < M) H1[(size_t)row * NF2 + col] = f2bf(acc[m][n][j]);
      }
    }
  }
}

// ---------------- degree / CSR build ----------------
__global__ void k_deg(const int* __restrict__ EI, int E, u32* __restrict__ deg) {
  int e = blockIdx.x * 256 + threadIdx.x;
  if (e < E) atomicAdd(&deg[EI[E + e]], 1u);
}

__global__ __launch_bounds__(1024) void k_scan1(const u32* __restrict__ deg,
                                                u32* __restrict__ rowptr,
                                                u32* __restrict__ bsum, int Nn) {
  __shared__ u32 sm[1024];
  int t = threadIdx.x;
  int i = blockIdx.x * 1024 + t;
  u32 v = (i < Nn) ? deg[i] : 0u;
  sm[t] = v;
  __syncthreads();
  #pragma unroll
  for (int off = 1; off < 1024; off <<= 1) {
    u32 x = (t >= off) ? sm[t - off] : 0u;
    __syncthreads();
    sm[t] += x;
    __syncthreads();
  }
  u32 incl = sm[t];
  if (i < Nn) rowptr[i] = incl - v;
  if (t == 1023) bsum[blockIdx.x] = incl;
}

__global__ void k_scan2(const u32* __restrict__ bsum, u32* __restrict__ boff, int nc) {
  __shared__ u32 sm[128];
  int t = threadIdx.x;
  u32 v = (t < nc) ? bsum[t] : 0u;
  sm[t] = v;
  __syncthreads();
  #pragma unroll
  for (int off = 1; off < 128; off <<= 1) {
    u32 x = (t >= off) ? sm[t - off] : 0u;
    __syncthreads();
    sm[t] += x;
    __syncthreads();
  }
  if (t < nc) boff[t] = sm[t] - v;
}

__global__ void k_scan3(u32* __restrict__ rowptr, const u32* __restrict__ boff,
                        u32* __restrict__ cursor, const u32* __restrict__ deg,
                        float* __restrict__ dinv, int Nn, int E) {
  int i = blockIdx.x * 256 + threadIdx.x;
  if (i < Nn) {
    u32 rp = rowptr[i] + boff[i >> 10];
    rowptr[i] = rp;
    cursor[i] = rp;
    dinv[i] = rsqrtf((float)deg[i] + 1.0f);
  }
  if (i == 0) rowptr[Nn] = (u32)E;
}

__global__ void k_fill(const int* __restrict__ EI, int E, int* __restrict__ cursor,
                       int* __restrict__ csr) {
  int e = blockIdx.x * 256 + threadIdx.x;
  if (e < E) {
    int s = EI[e], d = EI[E + e];
    int pos = atomicAdd(&cursor[d], 1);
    csr[pos] = s;
  }
}

// ---------------- fused: agg1 + self + b1 + relu + @W2 -> H2 [N,2] ----------------
__global__ __launch_bounds__(256) void k_agg1(const u16* __restrict__ H1,
                                              const int* __restrict__ csr,
                                              const u32* __restrict__ rowptr,
                                              const float* __restrict__ dinv,
                                              const float* __restrict__ B1,
                                              const float* __restrict__ W2,
                                              float* __restrict__ H2, int Nn) {
  int node = (blockIdx.x << 2) + (threadIdx.x >> 6);
  if (node >= Nn) return;
  int lane = threadIdx.x & 63;
  int rp0 = (int)rowptr[node], rp1 = (int)rowptr[node + 1];
  float dvi = dinv[node];
  float a0 = 0.f, a1 = 0.f, a2 = 0.f, a3 = 0.f;
  for (int e = rp0; e < rp1; e += 2) {
    int s0 = csr[e];
    bool has1 = (e + 1 < rp1);
    int s1 = has1 ? csr[e + 1] : s0;
    float n0 = dinv[s0] * dvi;
    float n1 = has1 ? dinv[s1] * dvi : 0.f;
    ushort4 v0 = ((const ushort4*)(H1 + (size_t)s0 * NF2))[lane];
    ushort4 v1 = ((const ushort4*)(H1 + (size_t)s1 * NF2))[lane];
    a0 += n0 * bf2f(v0.x) + n1 * bf2f(v1.x);
    a1 += n0 * bf2f(v0.y) + n1 * bf2f(v1.y);
    a2 += n0 * bf2f(v0.z) + n1 * bf2f(v1.z);
    a3 += n0 * bf2f(v0.w) + n1 * bf2f(v1.w);
  }
  {   // self-loop: norm = dinv^2 = 1/deg
    float ns = dvi * dvi;
    ushort4 v = ((const ushort4*)(H1 + (size_t)node * NF2))[lane];
    a0 += ns * bf2f(v.x);
    a1 += ns * bf2f(v.y);
    a2 += ns * bf2f(v.z);
    a3 += ns * bf2f(v.w);
  }
  float4 bb = ((const float4*)B1)[lane];
  float r0 = fmaxf(a0 + bb.x, 0.f);
  float r1 = fmaxf(a1 + bb.y, 0.f);
  float r2 = fmaxf(a2 + bb.z, 0.f);
  float r3 = fmaxf(a3 + bb.w, 0.f);
  float4 wA = ((const float4*)W2)[2 * lane];       // W2[4l..4l+1][0..1]
  float4 wB = ((const float4*)W2)[2 * lane + 1];   // W2[4l+2..4l+3][0..1]
  float p0 = r0 * wA.x + r1 * wA.z + r2 * wB.x + r3 * wB.z;
  float p1 = r0 * wA.y + r1 * wA.w + r2 * wB.y + r3 * wB.w;
  #pragma unroll
  for (int o = 32; o; o >>= 1) {
    p0 += __shfl_xor(p0, o);
    p1 += __shfl_xor(p1, o);
  }
  if (lane == 0) {
    H2[2 * (size_t)node]     = p0;
    H2[2 * (size_t)node + 1] = p1;
  }
}

// ---------------- layer-2 edge aggregation, pooled directly into graph bins ----------------
__global__ __launch_bounds__(256) void k_l2e(const int* __restrict__ EI, int E,
                                             const float* __restrict__ dinv,
                                             const float* __restrict__ H2,
                                             const int* __restrict__ batch,
                                             float* __restrict__ accg) {
  __shared__ float sb[1024];
  for (int i = threadIdx.x; i < 1024; i += 256) sb[i] = 0.f;
  __syncthreads();
  for (int e = blockIdx.x * 256 + threadIdx.x; e < E; e += gridDim.x * 256) {
    int s = EI[e], d = EI[E + e];
    float nrm = dinv[s] * dinv[d];
    float2 hv = *(const float2*)(H2 + 2 * (size_t)s);
    int g = batch[d];
    atomicAdd(&sb[2 * g],     nrm * hv.x);
    atomicAdd(&sb[2 * g + 1], nrm * hv.y);
  }
  __syncthreads();
  for (int i = threadIdx.x; i < 1024; i += 256)
    if (sb[i] != 0.f) atomicAdd(&accg[i], sb[i]);
}

// layer-2 self-loop + per-graph counts
__global__ __launch_bounds__(256) void k_l2n(int Nn, const float* __restrict__ dinv,
                                             const float* __restrict__ H2,
                                             const int* __restrict__ batch,
                                             float* __restrict__ accg,
                                             u32* __restrict__ gcnt) {
  __shared__ float sb[1024];
  __shared__ u32 sc[512];
  for (int i = threadIdx.x; i < 1024; i += 256) sb[i] = 0.f;
  for (int i = threadIdx.x; i < 512; i += 256) sc[i] = 0u;
  __syncthreads();
  for (int i = blockIdx.x * 256 + threadIdx.x; i < Nn; i += gridDim.x * 256) {
    int g = batch[i];
    float dv = dinv[i];
    float ns = dv * dv;
    float2 hv = *(const float2*)(H2 + 2 * (size_t)i);
    atomicAdd(&sb[2 * g],     ns * hv.x);
    atomicAdd(&sb[2 * g + 1], ns * hv.y);
    atomicAdd(&sc[g], 1u);
  }
  __syncthreads();
  for (int i = threadIdx.x; i < 1024; i += 256)
    if (sb[i] != 0.f) atomicAdd(&accg[i], sb[i]);
  for (int i = threadIdx.x; i < 512; i += 256)
    if (sc[i]) atomicAdd(&gcnt[i], sc[i]);
}

__global__ void k_final(const float* __restrict__ accg, const u32* __restrict__ gcnt,
                        const float* __restrict__ B2, float* __restrict__ out) {
  int i = blockIdx.x * 256 + threadIdx.x;
  if (i < 1024) {
    int g = i >> 1, c = i & 1;
    float cnt = (float)gcnt[g];
    float s = accg[i] + cnt * B2[c];
    out[i] = s / fmaxf(cnt, 1.0f);
  }
}

extern "C" void kernel_launch(void* const* d_in, const int* in_sizes, int n_in,
                              void* d_out, int out_size, void* d_ws, size_t ws_size,
                              hipStream_t stream) {
  const float* X     = (const float*)d_in[0];
  const int*   EI    = (const int*)d_in[1];
  const int*   BATCH = (const int*)d_in[2];
  const float* W1    = (const float*)d_in[3];
  const float* B1    = (const float*)d_in[4];
  const float* W2    = (const float*)d_in[5];
  const float* B2    = (const float*)d_in[6];
  const int Nn = in_sizes[0] / NF1;      // 100000
  const int E  = in_sizes[1] / 2;        // 1600000
  float* OUT = (float*)d_out;
  (void)n_in; (void)out_size; (void)ws_size;

  char* w = (char*)d_ws;
  size_t off = 0;
  auto alloc = [&](size_t bytes) -> void* {
    void* p = w + off;
    off = (off + bytes + 511) & ~(size_t)511;
    return p;
  };
  u32*   deg    = (u32*)alloc((size_t)Nn * 4);
  u32*   rowptr = (u32*)alloc(((size_t)Nn + 1) * 4);
  u32*   cursor = (u32*)alloc((size_t)Nn * 4);
  u32*   bsum   = (u32*)alloc(512);
  u32*   boff   = (u32*)alloc(512);
  float* dinv   = (float*)alloc((size_t)Nn * 4);
  int*   csr    = (int*)alloc((size_t)E * 4);
  u16*   H1     = (u16*)alloc((size_t)Nn * NF2 * 2);
  float* H2     = (float*)alloc((size_t)Nn * 2 * 4);
  float* accg   = (float*)alloc(1536 * 4);   // 1024 f32 sums + 512 u32 counts
  u32*   gcnt   = (u32*)(accg + 1024);
  u16*   W1T    = (u16*)alloc((size_t)NF1 * NF2 * 2);

  const int NC = (Nn + 1023) >> 10;          // scan chunks (98), must be <= 128

  hipLaunchKernelGGL(k_zero, dim3((Nn + 255) / 256), dim3(256), 0, stream, deg, Nn);
  hipLaunchKernelGGL(k_zero, dim3(6), dim3(256), 0, stream, (u32*)accg, 1536);
  hipLaunchKernelGGL(k_w1t, dim3((NF1 * NF2 + 255) / 256), dim3(256), 0, stream, W1, W1T);
  hipLaunchKernelGGL(k_gemm, dim3((Nn + 127) / 128, 2), dim3(256), 0, stream, X, W1T, H1, Nn);
  hipLaunchKernelGGL(k_deg, dim3((E + 255) / 256), dim3(256), 0, stream, EI, E, deg);
  hipLaunchKernelGGL(k_scan1, dim3(NC), dim3(1024), 0, stream, deg, rowptr, bsum, Nn);
  hipLaunchKernelGGL(k_scan2, dim3(1), dim3(128), 0, stream, bsum, boff, NC);
  hipLaunchKernelGGL(k_scan3, dim3((Nn + 255) / 256), dim3(256), 0, stream,
                     rowptr, boff, cursor, deg, dinv, Nn, E);
  hipLaunchKernelGGL(k_fill, dim3((E + 255) / 256), dim3(256), 0, stream,
                     EI, E, (int*)cursor, csr);
  hipLaunchKernelGGL(k_agg1, dim3((Nn + 3) / 4), dim3(256), 0, stream,
                     H1, csr, rowptr, dinv, B1, W2, H2, Nn);
  hipLaunchKernelGGL(k_l2e, dim3(512), dim3(256), 0, stream, EI, E, dinv, H2, BATCH, accg);
  hipLaunchKernelGGL(k_l2n, dim3(256), dim3(256), 0, stream, Nn, dinv, H2, BATCH, accg, gcnt);
  hipLaunchKernelGGL(k_final, dim3(4), dim3(256), 0, stream, accg, gcnt, B2, OUT);
}

// Round 6
// 566.024 us; speedup vs baseline: 1.2239x; 1.0352x over previous
//
#include <hip/hip_runtime.h>

typedef unsigned short u16;
typedef unsigned int   u32;
typedef __bf16 bf16x8 __attribute__((ext_vector_type(8)));
typedef float  f32x4  __attribute__((ext_vector_type(4)));
typedef u32    u32x4  __attribute__((ext_vector_type(4)));

#define NF1 768   // input feature dim
#define NF2 256   // hidden feature dim

__device__ __forceinline__ u16 f2bf(float f) {
  u32 u = __builtin_bit_cast(u32, f);
  u += 0x7fffu + ((u >> 16) & 1u);      // RTNE
  return (u16)(u >> 16);
}
__device__ __forceinline__ float bf2f(u16 h) {
  return __builtin_bit_cast(float, ((u32)h) << 16);
}

// async global->LDS, 16B per lane. LDS dest is wave-uniform base + lane*16.
__device__ __forceinline__ void gll16(const void* g, void* l) {
  __builtin_amdgcn_global_load_lds(
      (const __attribute__((address_space(1))) unsigned int*)g,
      (__attribute__((address_space(3))) unsigned int*)l, 16, 0, 0);
}

// ---------------- utility ----------------
__global__ void k_zero(u32* __restrict__ p, int n) {
  int i = blockIdx.x * 256 + threadIdx.x;
  if (i < n) p[i] = 0u;
}

// W1 [768,256] f32 row-major -> W1T [256,768] bf16
__global__ void k_w1t(const float* __restrict__ W1, u16* __restrict__ W1T) {
  int idx = blockIdx.x * 256 + threadIdx.x;
  if (idx < NF1 * NF2) {
    int k = idx >> 8, j = idx & 255;
    W1T[(size_t)j * NF1 + k] = f2bf(W1[idx]);
  }
}

// ---------------- GEMM1: H1 = bf16(x @ W1), [M,256] bf16 ----------------
// R6: m97 structure — global_load_lds direct staging (no VGPR roundtrip, no
// pack VALU, no staging ds_writes), single-buffered 48KB LDS (3 blocks/CU),
// 2 barriers/iter. A kept f32 in LDS, converted via v_cvt_pk_bf16_f32 at
// frag-read time. Bank conflicts avoided by PRE-SWIZZLED per-lane global
// source + same XOR perm on the LDS read (rule #21: linear dest,
// inverse-perm source, perm read). Perms (16B units within a row):
//   A (16 units/row): perm_a(row) = ((row&7)<<1) | ((row>>3)&1)
//   B ( 8 units/col): perm_b(col) = col&7
__global__ __launch_bounds__(256) void k_gemm(const float* __restrict__ X,
                                              const u16* __restrict__ W1T,
                                              u16* __restrict__ H1, int M) {
  __shared__ float lsA[128 * 64];   // 32 KB: byte addr = row*256 + phys_unit*16
  __shared__ u16   lsB[128 * 64];   // 16 KB: byte addr = col*128 + phys_unit*16
  const int t    = threadIdx.x;
  const int m0   = blockIdx.x * 128;
  const int n0   = blockIdx.y * 128;
  const int lane = t & 63;
  const int wid  = t >> 6;
  const int wr   = wid >> 1, wc = wid & 1;

  // ---- staging source addresses (per-lane, pre-swizzled) ----
  // A call i (i=0..7): wave stages rows i*16 + wid*4 .. +4 (1KB contiguous).
  // lane's row = i*16 + rowbase, phys unit = lane&15.
  const int rowbase = wid * 4 + (lane >> 4);                      // 0..15
  const int perm_s  = ((rowbase & 7) << 1) | ((rowbase >> 3) & 1); // == perm_a(row)
  const float* srcA[8];
  #pragma unroll
  for (int i = 0; i < 8; ++i) {
    int gr = m0 + i * 16 + rowbase;
    if (gr > M - 1) gr = M - 1;                                   // clamp (valid data, rows >= M discarded)
    srcA[i] = X + (size_t)gr * NF1 + (((lane & 15) ^ perm_s) * 4);
  }
  // B call j (j=0..3): wave stages cols j*32 + wid*8 .. +8. phys unit = lane&7.
  const int colbase = wid * 8 + (lane >> 3);                      // col&7 == lane>>3
  const u16* srcB[4];
  #pragma unroll
  for (int j = 0; j < 4; ++j) {
    int gc = n0 + j * 32 + colbase;
    srcB[j] = W1T + (size_t)gc * NF1 + (((lane & 7) ^ (lane >> 3)) * 8);
  }

  f32x4 acc[4][4];
  #pragma unroll
  for (int m = 0; m < 4; ++m)
    #pragma unroll
    for (int n = 0; n < 4; ++n) { f32x4 z = {0.f, 0.f, 0.f, 0.f}; acc[m][n] = z; }

  const int lm     = lane & 15;
  const int l4     = lane >> 4;
  const int perm_r = ((lane & 7) << 1) | ((lane >> 3) & 1);       // == perm_a(frag row)

  const int NT = NF1 / 64;   // 12
  for (int kt = 0; kt < NT; ++kt) {
    // ---- stage tile kt: 12 global_load_lds, no VGPR roundtrip ----
    #pragma unroll
    for (int i = 0; i < 8; ++i)
      gll16(srcA[i] + kt * 64, &lsA[(i * 16 + wid * 4) * 64]);
    #pragma unroll
    for (int j = 0; j < 4; ++j)
      gll16(srcB[j] + kt * 64, &lsB[(j * 32 + wid * 8) * 64]);
    __syncthreads();   // compiler emits vmcnt(0) drain before s_barrier

    // ---- compute ----
    #pragma unroll
    for (int ks = 0; ks < 2; ++ks) {
      bf16x8 af[4], bfr[4];
      #pragma unroll
      for (int m = 0; m < 4; ++m) {
        int row  = wr * 64 + m * 16 + lm;
        int c    = ks * 4 + l4;                 // 32B chunk index (0..7)
        int ulo  = (2 * c) ^ perm_r;            // phys 16B unit of k0..k0+3
        const char* base = (const char*)lsA + row * 256;
        float4 L = *(const float4*)(base + ulo * 16);
        float4 H = *(const float4*)(base + (ulo ^ 1) * 16);
        u32 w0, w1, w2, w3;
        asm("v_cvt_pk_bf16_f32 %0, %1, %2" : "=v"(w0) : "v"(L.x), "v"(L.y));
        asm("v_cvt_pk_bf16_f32 %0, %1, %2" : "=v"(w1) : "v"(L.z), "v"(L.w));
        asm("v_cvt_pk_bf16_f32 %0, %1, %2" : "=v"(w2) : "v"(H.x), "v"(H.y));
        asm("v_cvt_pk_bf16_f32 %0, %1, %2" : "=v"(w3) : "v"(H.z), "v"(H.w));
        u32x4 uw = {w0, w1, w2, w3};
        af[m] = __builtin_bit_cast(bf16x8, uw);
      }
      #pragma unroll
      for (int n = 0; n < 4; ++n) {
        int col = wc * 64 + n * 16 + lm;
        int u   = ks * 4 + l4;
        int ph  = u ^ (lane & 7);               // perm_b(col) = col&7 = lane&7
        bfr[n] = *(const bf16x8*)((const char*)lsB + col * 128 + ph * 16);
      }
      #pragma unroll
      for (int m = 0; m < 4; ++m)
        #pragma unroll
        for (int n = 0; n < 4; ++n)
          acc[m][n] = __builtin_amdgcn_mfma_f32_16x16x32_bf16(af[m], bfr[n], acc[m][n], 0, 0, 0);
    }
    __syncthreads();   // tile fully consumed before next stage overwrites
  }

  // epilogue: D col=lane&15, row=(lane>>4)*4+j  (m89-verified layout)
  #pragma unroll
  for (int m = 0; m < 4; ++m) {
    int rowb = m0 + wr * 64 + m * 16 + (lane >> 4) * 4;
    #pragma unroll
    for (int n = 0; n < 4; ++n) {
      int col = n0 + wc * 64 + n * 16 + (lane & 15);
      #pragma unroll
      for (int j = 0; j < 4; ++j) {
        int row = rowb + j;
        if (row < M) H1[(size_t)row * NF2 + col] = f2bf(acc[m][n][j]);
      }
    }
  }
}

// ---------------- degree / CSR build ----------------
__global__ void k_deg(const int* __restrict__ EI, int E, u32* __restrict__ deg) {
  int e = blockIdx.x * 256 + threadIdx.x;
  if (e < E) atomicAdd(&deg[EI[E + e]], 1u);
}

__global__ __launch_bounds__(1024) void k_scan1(const u32* __restrict__ deg,
                                                u32* __restrict__ rowptr,
                                                u32* __restrict__ bsum, int Nn) {
  __shared__ u32 sm[1024];
  int t = threadIdx.x;
  int i = blockIdx.x * 1024 + t;
  u32 v = (i < Nn) ? deg[i] : 0u;
  sm[t] = v;
  __syncthreads();
  #pragma unroll
  for (int off = 1; off < 1024; off <<= 1) {
    u32 x = (t >= off) ? sm[t - off] : 0u;
    __syncthreads();
    sm[t] += x;
    __syncthreads();
  }
  u32 incl = sm[t];
  if (i < Nn) rowptr[i] = incl - v;
  if (t == 1023) bsum[blockIdx.x] = incl;
}

__global__ void k_scan2(const u32* __restrict__ bsum, u32* __restrict__ boff, int nc) {
  __shared__ u32 sm[128];
  int t = threadIdx.x;
  u32 v = (t < nc) ? bsum[t] : 0u;
  sm[t] = v;
  __syncthreads();
  #pragma unroll
  for (int off = 1; off < 128; off <<= 1) {
    u32 x = (t >= off) ? sm[t - off] : 0u;
    __syncthreads();
    sm[t] += x;
    __syncthreads();
  }
  if (t < nc) boff[t] = sm[t] - v;
}

__global__ void k_scan3(u32* __restrict__ rowptr, const u32* __restrict__ boff,
                        u32* __restrict__ cursor, const u32* __restrict__ deg,
                        float* __restrict__ dinv, int Nn, int E) {
  int i = blockIdx.x * 256 + threadIdx.x;
  if (i < Nn) {
    u32 rp = rowptr[i] + boff[i >> 10];
    rowptr[i] = rp;
    cursor[i] = rp;
    dinv[i] = rsqrtf((float)deg[i] + 1.0f);
  }
  if (i == 0) rowptr[Nn] = (u32)E;
}

__global__ void k_fill(const int* __restrict__ EI, int E, int* __restrict__ cursor,
                       int* __restrict__ csr) {
  int e = blockIdx.x * 256 + threadIdx.x;
  if (e < E) {
    int s = EI[e], d = EI[E + e];
    int pos = atomicAdd(&cursor[d], 1);
    csr[pos] = s;
  }
}

// ---------------- fused: agg1 + self + b1 + relu + @W2 -> H2 [N,2] ----------------
__global__ __launch_bounds__(256) void k_agg1(const u16* __restrict__ H1,
                                              const int* __restrict__ csr,
                                              const u32* __restrict__ rowptr,
                                              const float* __restrict__ dinv,
                                              const float* __restrict__ B1,
                                              const float* __restrict__ W2,
                                              float* __restrict__ H2, int Nn) {
  int node = (blockIdx.x << 2) + (threadIdx.x >> 6);
  if (node >= Nn) return;
  int lane = threadIdx.x & 63;
  int rp0 = (int)rowptr[node], rp1 = (int)rowptr[node + 1];
  float dvi = dinv[node];
  float a0 = 0.f, a1 = 0.f, a2 = 0.f, a3 = 0.f;
  for (int e = rp0; e < rp1; e += 2) {
    int s0 = csr[e];
    bool has1 = (e + 1 < rp1);
    int s1 = has1 ? csr[e + 1] : s0;
    float n0 = dinv[s0] * dvi;
    float n1 = has1 ? dinv[s1] * dvi : 0.f;
    ushort4 v0 = ((const ushort4*)(H1 + (size_t)s0 * NF2))[lane];
    ushort4 v1 = ((const ushort4*)(H1 + (size_t)s1 * NF2))[lane];
    a0 += n0 * bf2f(v0.x) + n1 * bf2f(v1.x);
    a1 += n0 * bf2f(v0.y) + n1 * bf2f(v1.y);
    a2 += n0 * bf2f(v0.z) + n1 * bf2f(v1.z);
    a3 += n0 * bf2f(v0.w) + n1 * bf2f(v1.w);
  }
  {   // self-loop: norm = dinv^2 = 1/deg
    float ns = dvi * dvi;
    ushort4 v = ((const ushort4*)(H1 + (size_t)node * NF2))[lane];
    a0 += ns * bf2f(v.x);
    a1 += ns * bf2f(v.y);
    a2 += ns * bf2f(v.z);
    a3 += ns * bf2f(v.w);
  }
  float4 bb = ((const float4*)B1)[lane];
  float r0 = fmaxf(a0 + bb.x, 0.f);
  float r1 = fmaxf(a1 + bb.y, 0.f);
  float r2 = fmaxf(a2 + bb.z, 0.f);
  float r3 = fmaxf(a3 + bb.w, 0.f);
  float4 wA = ((const float4*)W2)[2 * lane];       // W2[4l..4l+1][0..1]
  float4 wB = ((const float4*)W2)[2 * lane + 1];   // W2[4l+2..4l+3][0..1]
  float p0 = r0 * wA.x + r1 * wA.z + r2 * wB.x + r3 * wB.z;
  float p1 = r0 * wA.y + r1 * wA.w + r2 * wB.y + r3 * wB.w;
  #pragma unroll
  for (int o = 32; o; o >>= 1) {
    p0 += __shfl_xor(p0, o);
    p1 += __shfl_xor(p1, o);
  }
  if (lane == 0) {
    H2[2 * (size_t)node]     = p0;
    H2[2 * (size_t)node + 1] = p1;
  }
}

// ---------------- layer-2 edge aggregation, pooled directly into graph bins ----------------
__global__ __launch_bounds__(256) void k_l2e(const int* __restrict__ EI, int E,
                                             const float* __restrict__ dinv,
                                             const float* __restrict__ H2,
                                             const int* __restrict__ batch,
                                             float* __restrict__ accg) {
  __shared__ float sb[1024];
  for (int i = threadIdx.x; i < 1024; i += 256) sb[i] = 0.f;
  __syncthreads();
  for (int e = blockIdx.x * 256 + threadIdx.x; e < E; e += gridDim.x * 256) {
    int s = EI[e], d = EI[E + e];
    float nrm = dinv[s] * dinv[d];
    float2 hv = *(const float2*)(H2 + 2 * (size_t)s);
    int g = batch[d];
    atomicAdd(&sb[2 * g],     nrm * hv.x);
    atomicAdd(&sb[2 * g + 1], nrm * hv.y);
  }
  __syncthreads();
  for (int i = threadIdx.x; i < 1024; i += 256)
    if (sb[i] != 0.f) atomicAdd(&accg[i], sb[i]);
}

// layer-2 self-loop + per-graph counts
__global__ __launch_bounds__(256) void k_l2n(int Nn, const float* __restrict__ dinv,
                                             const float* __restrict__ H2,
                                             const int* __restrict__ batch,
                                             float* __restrict__ accg,
                                             u32* __restrict__ gcnt) {
  __shared__ float sb[1024];
  __shared__ u32 sc[512];
  for (int i = threadIdx.x; i < 1024; i += 256) sb[i] = 0.f;
  for (int i = threadIdx.x; i < 512; i += 256) sc[i] = 0u;
  __syncthreads();
  for (int i = blockIdx.x * 256 + threadIdx.x; i < Nn; i += gridDim.x * 256) {
    int g = batch[i];
    float dv = dinv[i];
    float ns = dv * dv;
    float2 hv = *(const float2*)(H2 + 2 * (size_t)i);
    atomicAdd(&sb[2 * g],     ns * hv.x);
    atomicAdd(&sb[2 * g + 1], ns * hv.y);
    atomicAdd(&sc[g], 1u);
  }
  __syncthreads();
  for (int i = threadIdx.x; i < 1024; i += 256)
    if (sb[i] != 0.f) atomicAdd(&accg[i], sb[i]);
  for (int i = threadIdx.x; i < 512; i += 256)
    if (sc[i]) atomicAdd(&gcnt[i], sc[i]);
}

__global__ void k_final(const float* __restrict__ accg, const u32* __restrict__ gcnt,
                        const float* __restrict__ B2, float* __restrict__ out) {
  int i = blockIdx.x * 256 + threadIdx.x;
  if (i < 1024) {
    int g = i >> 1, c = i & 1;
    float cnt = (float)gcnt[g];
    float s = accg[i] + cnt * B2[c];
    out[i] = s / fmaxf(cnt, 1.0f);
  }
}

extern "C" void kernel_launch(void* const* d_in, const int* in_sizes, int n_in,
                              void* d_out, int out_size, void* d_ws, size_t ws_size,
                              hipStream_t stream) {
  const float* X     = (const float*)d_in[0];
  const int*   EI    = (const int*)d_in[1];
  const int*   BATCH = (const int*)d_in[2];
  const float* W1    = (const float*)d_in[3];
  const float* B1    = (const float*)d_in[4];
  const float* W2    = (const float*)d_in[5];
  const float* B2    = (const float*)d_in[6];
  const int Nn = in_sizes[0] / NF1;      // 100000
  const int E  = in_sizes[1] / 2;        // 1600000
  float* OUT = (float*)d_out;
  (void)n_in; (void)out_size; (void)ws_size;

  char* w = (char*)d_ws;
  size_t off = 0;
  auto alloc = [&](size_t bytes) -> void* {
    void* p = w + off;
    off = (off + bytes + 511) & ~(size_t)511;
    return p;
  };
  u32*   deg    = (u32*)alloc((size_t)Nn * 4);
  u32*   rowptr = (u32*)alloc(((size_t)Nn + 1) * 4);
  u32*   cursor = (u32*)alloc((size_t)Nn * 4);
  u32*   bsum   = (u32*)alloc(512);
  u32*   boff   = (u32*)alloc(512);
  float* dinv   = (float*)alloc((size_t)Nn * 4);
  int*   csr    = (int*)alloc((size_t)E * 4);
  u16*   H1     = (u16*)alloc((size_t)Nn * NF2 * 2);
  float* H2     = (float*)alloc((size_t)Nn * 2 * 4);
  float* accg   = (float*)alloc(1536 * 4);   // 1024 f32 sums + 512 u32 counts
  u32*   gcnt   = (u32*)(accg + 1024);
  u16*   W1T    = (u16*)alloc((size_t)NF1 * NF2 * 2);

  const int NC = (Nn + 1023) >> 10;          // scan chunks (98), must be <= 128

  hipLaunchKernelGGL(k_zero, dim3((Nn + 255) / 256), dim3(256), 0, stream, deg, Nn);
  hipLaunchKernelGGL(k_zero, dim3(6), dim3(256), 0, stream, (u32*)accg, 1536);
  hipLaunchKernelGGL(k_w1t, dim3((NF1 * NF2 + 255) / 256), dim3(256), 0, stream, W1, W1T);
  hipLaunchKernelGGL(k_gemm, dim3((Nn + 127) / 128, 2), dim3(256), 0, stream, X, W1T, H1, Nn);
  hipLaunchKernelGGL(k_deg, dim3((E + 255) / 256), dim3(256), 0, stream, EI, E, deg);
  hipLaunchKernelGGL(k_scan1, dim3(NC), dim3(1024), 0, stream, deg, rowptr, bsum, Nn);
  hipLaunchKernelGGL(k_scan2, dim3(1), dim3(128), 0, stream, bsum, boff, NC);
  hipLaunchKernelGGL(k_scan3, dim3((Nn + 255) / 256), dim3(256), 0, stream,
                     rowptr, boff, cursor, deg, dinv, Nn, E);
  hipLaunchKernelGGL(k_fill, dim3((E + 255) / 256), dim3(256), 0, stream,
                     EI, E, (int*)cursor, csr);
  hipLaunchKernelGGL(k_agg1, dim3((Nn + 3) / 4), dim3(256), 0, stream,
                     H1, csr, rowptr, dinv, B1, W2, H2, Nn);
  hipLaunchKernelGGL(k_l2e, dim3(512), dim3(256), 0, stream, EI, E, dinv, H2, BATCH, accg);
  hipLaunchKernelGGL(k_l2n, dim3(256), dim3(256), 0, stream, Nn, dinv, H2, BATCH, accg, gcnt);
  hipLaunchKernelGGL(k_final, dim3(4), dim3(256), 0, stream, accg, gcnt, B2, OUT);
}

// Round 7
// 500.907 us; speedup vs baseline: 1.3830x; 1.1300x over previous
//
#include <hip/hip_runtime.h>

typedef unsigned short u16;
typedef unsigned int   u32;
typedef __bf16 bf16x8 __attribute__((ext_vector_type(8)));
typedef float  f32x4  __attribute__((ext_vector_type(4)));
typedef u32    u32x4  __attribute__((ext_vector_type(4)));
typedef u16    u16x8  __attribute__((ext_vector_type(8)));

#define NF1 768   // input feature dim
#define NF2 256   // hidden feature dim

__device__ __forceinline__ u16 f2bf(float f) {
  u32 u = __builtin_bit_cast(u32, f);
  u += 0x7fffu + ((u >> 16) & 1u);      // RTNE
  return (u16)(u >> 16);
}
__device__ __forceinline__ float bf2f(u16 h) {
  return __builtin_bit_cast(float, ((u32)h) << 16);
}

// async global->LDS, 16B per lane. LDS dest is wave-uniform base + lane*16.
__device__ __forceinline__ void gll16(const void* g, void* l) {
  __builtin_amdgcn_global_load_lds(
      (const __attribute__((address_space(1))) unsigned int*)g,
      (__attribute__((address_space(3))) unsigned int*)l, 16, 0, 0);
}

// ---------------- utility ----------------
__global__ void k_zero(u32* __restrict__ p, int n) {
  int i = blockIdx.x * 256 + threadIdx.x;
  if (i < n) p[i] = 0u;
}

// W1 [768,256] f32 row-major -> W1T [256,768] bf16
__global__ void k_w1t(const float* __restrict__ W1, u16* __restrict__ W1T) {
  int idx = blockIdx.x * 256 + threadIdx.x;
  if (idx < NF1 * NF2) {
    int k = idx >> 8, j = idx & 255;
    W1T[(size_t)j * NF1 + k] = f2bf(W1[idx]);
  }
}

// ---------------- GEMM1: H1 = bf16(x @ W1), [M,256] bf16 ----------------
// R6 structure (validated): global_load_lds direct staging, single-buffered
// 48KB LDS, pre-swizzled source + perm read (rule #21).
__global__ __launch_bounds__(256) void k_gemm(const float* __restrict__ X,
                                              const u16* __restrict__ W1T,
                                              u16* __restrict__ H1, int M) {
  __shared__ float lsA[128 * 64];   // 32 KB: byte addr = row*256 + phys_unit*16
  __shared__ u16   lsB[128 * 64];   // 16 KB: byte addr = col*128 + phys_unit*16
  const int t    = threadIdx.x;
  const int m0   = blockIdx.x * 128;
  const int n0   = blockIdx.y * 128;
  const int lane = t & 63;
  const int wid  = t >> 6;
  const int wr   = wid >> 1, wc = wid & 1;

  const int rowbase = wid * 4 + (lane >> 4);                      // 0..15
  const int perm_s  = ((rowbase & 7) << 1) | ((rowbase >> 3) & 1); // == perm_a(row)
  const float* srcA[8];
  #pragma unroll
  for (int i = 0; i < 8; ++i) {
    int gr = m0 + i * 16 + rowbase;
    if (gr > M - 1) gr = M - 1;
    srcA[i] = X + (size_t)gr * NF1 + (((lane & 15) ^ perm_s) * 4);
  }
  const int colbase = wid * 8 + (lane >> 3);
  const u16* srcB[4];
  #pragma unroll
  for (int j = 0; j < 4; ++j) {
    int gc = n0 + j * 32 + colbase;
    srcB[j] = W1T + (size_t)gc * NF1 + (((lane & 7) ^ (lane >> 3)) * 8);
  }

  f32x4 acc[4][4];
  #pragma unroll
  for (int m = 0; m < 4; ++m)
    #pragma unroll
    for (int n = 0; n < 4; ++n) { f32x4 z = {0.f, 0.f, 0.f, 0.f}; acc[m][n] = z; }

  const int lm     = lane & 15;
  const int l4     = lane >> 4;
  const int perm_r = ((lane & 7) << 1) | ((lane >> 3) & 1);

  const int NT = NF1 / 64;   // 12
  for (int kt = 0; kt < NT; ++kt) {
    #pragma unroll
    for (int i = 0; i < 8; ++i)
      gll16(srcA[i] + kt * 64, &lsA[(i * 16 + wid * 4) * 64]);
    #pragma unroll
    for (int j = 0; j < 4; ++j)
      gll16(srcB[j] + kt * 64, &lsB[(j * 32 + wid * 8) * 64]);
    __syncthreads();

    #pragma unroll
    for (int ks = 0; ks < 2; ++ks) {
      bf16x8 af[4], bfr[4];
      #pragma unroll
      for (int m = 0; m < 4; ++m) {
        int row  = wr * 64 + m * 16 + lm;
        int c    = ks * 4 + l4;
        int ulo  = (2 * c) ^ perm_r;
        const char* base = (const char*)lsA + row * 256;
        float4 L = *(const float4*)(base + ulo * 16);
        float4 H = *(const float4*)(base + (ulo ^ 1) * 16);
        u32 w0, w1, w2, w3;
        asm("v_cvt_pk_bf16_f32 %0, %1, %2" : "=v"(w0) : "v"(L.x), "v"(L.y));
        asm("v_cvt_pk_bf16_f32 %0, %1, %2" : "=v"(w1) : "v"(L.z), "v"(L.w));
        asm("v_cvt_pk_bf16_f32 %0, %1, %2" : "=v"(w2) : "v"(H.x), "v"(H.y));
        asm("v_cvt_pk_bf16_f32 %0, %1, %2" : "=v"(w3) : "v"(H.z), "v"(H.w));
        u32x4 uw = {w0, w1, w2, w3};
        af[m] = __builtin_bit_cast(bf16x8, uw);
      }
      #pragma unroll
      for (int n = 0; n < 4; ++n) {
        int col = wc * 64 + n * 16 + lm;
        int u   = ks * 4 + l4;
        int ph  = u ^ (lane & 7);
        bfr[n] = *(const bf16x8*)((const char*)lsB + col * 128 + ph * 16);
      }
      #pragma unroll
      for (int m = 0; m < 4; ++m)
        #pragma unroll
        for (int n = 0; n < 4; ++n)
          acc[m][n] = __builtin_amdgcn_mfma_f32_16x16x32_bf16(af[m], bfr[n], acc[m][n], 0, 0, 0);
    }
    __syncthreads();
  }

  #pragma unroll
  for (int m = 0; m < 4; ++m) {
    int rowb = m0 + wr * 64 + m * 16 + (lane >> 4) * 4;
    #pragma unroll
    for (int n = 0; n < 4; ++n) {
      int col = n0 + wc * 64 + n * 16 + (lane & 15);
      #pragma unroll
      for (int j = 0; j < 4; ++j) {
        int row = rowb + j;
        if (row < M) H1[(size_t)row * NF2 + col] = f2bf(acc[m][n][j]);
      }
    }
  }
}

// ---------------- degree / CSR build ----------------
__global__ void k_deg(const int* __restrict__ EI, int E, u32* __restrict__ deg) {
  int e = blockIdx.x * 256 + threadIdx.x;
  if (e < E) atomicAdd(&deg[EI[E + e]], 1u);
}

__global__ __launch_bounds__(1024) void k_scan1(const u32* __restrict__ deg,
                                                u32* __restrict__ rowptr,
                                                u32* __restrict__ bsum, int Nn) {
  __shared__ u32 sm[1024];
  int t = threadIdx.x;
  int i = blockIdx.x * 1024 + t;
  u32 v = (i < Nn) ? deg[i] : 0u;
  sm[t] = v;
  __syncthreads();
  #pragma unroll
  for (int off = 1; off < 1024; off <<= 1) {
    u32 x = (t >= off) ? sm[t - off] : 0u;
    __syncthreads();
    sm[t] += x;
    __syncthreads();
  }
  u32 incl = sm[t];
  if (i < Nn) rowptr[i] = incl - v;
  if (t == 1023) bsum[blockIdx.x] = incl;
}

__global__ void k_scan2(const u32* __restrict__ bsum, u32* __restrict__ boff, int nc) {
  __shared__ u32 sm[128];
  int t = threadIdx.x;
  u32 v = (t < nc) ? bsum[t] : 0u;
  sm[t] = v;
  __syncthreads();
  #pragma unroll
  for (int off = 1; off < 128; off <<= 1) {
    u32 x = (t >= off) ? sm[t - off] : 0u;
    __syncthreads();
    sm[t] += x;
    __syncthreads();
  }
  if (t < nc) boff[t] = sm[t] - v;
}

__global__ void k_scan3(u32* __restrict__ rowptr, const u32* __restrict__ boff,
                        u32* __restrict__ cursor, const u32* __restrict__ deg,
                        float* __restrict__ dinv, int Nn, int E) {
  int i = blockIdx.x * 256 + threadIdx.x;
  if (i < Nn) {
    u32 rp = rowptr[i] + boff[i >> 10];
    rowptr[i] = rp;
    cursor[i] = rp;
    dinv[i] = rsqrtf((float)deg[i] + 1.0f);
  }
  if (i == 0) rowptr[Nn] = (u32)E;
}

__global__ void k_fill(const int* __restrict__ EI, int E, int* __restrict__ cursor,
                       int* __restrict__ csr) {
  int e = blockIdx.x * 256 + threadIdx.x;
  if (e < E) {
    int s = EI[e], d = EI[E + e];
    int pos = atomicAdd(&cursor[d], 1);
    csr[pos] = s;
  }
}

// ---------------- fused: agg1 + self + b1 + relu + @W2 -> H2 [N,2] ----------------
// R7: split-wave gather. Half-wave (32 lanes) covers a full 512B H1 row at
// 16B/lane; 4 edges in flight per half-wave iteration (8/wave) to cover
// L2/L3 gather latency (R6 was latency-bound: 2 loads in flight, all pipes
// idle). All loads issued before FMAs; named values only (rule #20).
__global__ __launch_bounds__(256) void k_agg1(const u16* __restrict__ H1,
                                              const int* __restrict__ csr,
                                              const u32* __restrict__ rowptr,
                                              const float* __restrict__ dinv,
                                              const float* __restrict__ B1,
                                              const float* __restrict__ W2,
                                              float* __restrict__ H2, int Nn) {
  int node = (blockIdx.x << 2) + (threadIdx.x >> 6);
  if (node >= Nn) return;
  const int lane = threadIdx.x & 63;
  const int hl   = lane >> 5;        // half-wave 0/1
  const int fo   = (lane & 31) * 8;  // feature offset (8 bf16 = 16B per lane)
  const int rp0 = (int)rowptr[node], rp1 = (int)rowptr[node + 1];
  const float dvi = dinv[node];

  float c0 = 0.f, c1 = 0.f, c2 = 0.f, c3 = 0.f,
        c4 = 0.f, c5 = 0.f, c6 = 0.f, c7 = 0.f;

  // half 0 handles edges {0,1,4,5, 8,9,12,13,...}+rp0, half 1 {2,3,6,7,...}+rp0
  for (int e = rp0 + 2 * hl; e < rp1; e += 8) {
    const int eA = e, eB = e + 1, eC = e + 4, eD = e + 5;
    const bool hB = eB < rp1, hC = eC < rp1, hD = eD < rp1;
    const int sA = csr[eA];
    const int sB = hB ? csr[eB] : sA;
    const int sC = hC ? csr[eC] : sA;
    const int sD = hD ? csr[eD] : sA;
    // issue all row loads first (4 x dwordx4 in flight per half-wave)
    const u16x8 rA = *(const u16x8*)(H1 + (size_t)sA * NF2 + fo);
    const u16x8 rB = *(const u16x8*)(H1 + (size_t)sB * NF2 + fo);
    const u16x8 rC = *(const u16x8*)(H1 + (size_t)sC * NF2 + fo);
    const u16x8 rD = *(const u16x8*)(H1 + (size_t)sD * NF2 + fo);
    const float nA = dinv[sA] * dvi;
    const float nB = hB ? dinv[sB] * dvi : 0.f;
    const float nC = hC ? dinv[sC] * dvi : 0.f;
    const float nD = hD ? dinv[sD] * dvi : 0.f;
    c0 += nA * bf2f(rA[0]) + nB * bf2f(rB[0]) + nC * bf2f(rC[0]) + nD * bf2f(rD[0]);
    c1 += nA * bf2f(rA[1]) + nB * bf2f(rB[1]) + nC * bf2f(rC[1]) + nD * bf2f(rD[1]);
    c2 += nA * bf2f(rA[2]) + nB * bf2f(rB[2]) + nC * bf2f(rC[2]) + nD * bf2f(rD[2]);
    c3 += nA * bf2f(rA[3]) + nB * bf2f(rB[3]) + nC * bf2f(rC[3]) + nD * bf2f(rD[3]);
    c4 += nA * bf2f(rA[4]) + nB * bf2f(rB[4]) + nC * bf2f(rC[4]) + nD * bf2f(rD[4]);
    c5 += nA * bf2f(rA[5]) + nB * bf2f(rB[5]) + nC * bf2f(rC[5]) + nD * bf2f(rD[5]);
    c6 += nA * bf2f(rA[6]) + nB * bf2f(rB[6]) + nC * bf2f(rC[6]) + nD * bf2f(rD[6]);
    c7 += nA * bf2f(rA[7]) + nB * bf2f(rB[7]) + nC * bf2f(rC[7]) + nD * bf2f(rD[7]);
  }

  // combine the two half-waves (lane l and l+32 hold the same feature slice)
  c0 += __shfl_xor(c0, 32);
  c1 += __shfl_xor(c1, 32);
  c2 += __shfl_xor(c2, 32);
  c3 += __shfl_xor(c3, 32);
  c4 += __shfl_xor(c4, 32);
  c5 += __shfl_xor(c5, 32);
  c6 += __shfl_xor(c6, 32);
  c7 += __shfl_xor(c7, 32);

  {   // self-loop: norm = dinv^2 = 1/deg (identical on both halves)
    const float ns = dvi * dvi;
    const u16x8 rs = *(const u16x8*)(H1 + (size_t)node * NF2 + fo);
    c0 += ns * bf2f(rs[0]); c1 += ns * bf2f(rs[1]);
    c2 += ns * bf2f(rs[2]); c3 += ns * bf2f(rs[3]);
    c4 += ns * bf2f(rs[4]); c5 += ns * bf2f(rs[5]);
    c6 += ns * bf2f(rs[6]); c7 += ns * bf2f(rs[7]);
  }

  const float4 bA = *(const float4*)(B1 + fo);
  const float4 bB = *(const float4*)(B1 + fo + 4);
  const float r0 = fmaxf(c0 + bA.x, 0.f), r1 = fmaxf(c1 + bA.y, 0.f);
  const float r2 = fmaxf(c2 + bA.z, 0.f), r3 = fmaxf(c3 + bA.w, 0.f);
  const float r4 = fmaxf(c4 + bB.x, 0.f), r5 = fmaxf(c5 + bB.y, 0.f);
  const float r6 = fmaxf(c6 + bB.z, 0.f), r7 = fmaxf(c7 + bB.w, 0.f);

  const float4* wp = (const float4*)(W2 + 2 * fo);   // W2[fo..fo+7][0..1]
  const float4 w0 = wp[0], w1 = wp[1], w2 = wp[2], w3 = wp[3];
  float p0 = r0 * w0.x + r1 * w0.z + r2 * w1.x + r3 * w1.z
           + r4 * w2.x + r5 * w2.z + r6 * w3.x + r7 * w3.z;
  float p1 = r0 * w0.y + r1 * w0.w + r2 * w1.y + r3 * w1.w
           + r4 * w2.y + r5 * w2.w + r6 * w3.y + r7 * w3.w;
  #pragma unroll
  for (int o = 16; o; o >>= 1) {
    p0 += __shfl_xor(p0, o);
    p1 += __shfl_xor(p1, o);
  }
  if (lane == 0) {
    H2[2 * (size_t)node]     = p0;
    H2[2 * (size_t)node + 1] = p1;
  }
}

// ---------------- layer-2 edge aggregation, pooled directly into graph bins ----------------
__global__ __launch_bounds__(256) void k_l2e(const int* __restrict__ EI, int E,
                                             const float* __restrict__ dinv,
                                             const float* __restrict__ H2,
                                             const int* __restrict__ batch,
                                             float* __restrict__ accg) {
  __shared__ float sb[1024];
  for (int i = threadIdx.x; i < 1024; i += 256) sb[i] = 0.f;
  __syncthreads();
  for (int e = blockIdx.x * 256 + threadIdx.x; e < E; e += gridDim.x * 256) {
    int s = EI[e], d = EI[E + e];
    float nrm = dinv[s] * dinv[d];
    float2 hv = *(const float2*)(H2 + 2 * (size_t)s);
    int g = batch[d];
    atomicAdd(&sb[2 * g],     nrm * hv.x);
    atomicAdd(&sb[2 * g + 1], nrm * hv.y);
  }
  __syncthreads();
  for (int i = threadIdx.x; i < 1024; i += 256)
    if (sb[i] != 0.f) atomicAdd(&accg[i], sb[i]);
}

// layer-2 self-loop + per-graph counts
__global__ __launch_bounds__(256) void k_l2n(int Nn, const float* __restrict__ dinv,
                                             const float* __restrict__ H2,
                                             const int* __restrict__ batch,
                                             float* __restrict__ accg,
                                             u32* __restrict__ gcnt) {
  __shared__ float sb[1024];
  __shared__ u32 sc[512];
  for (int i = threadIdx.x; i < 1024; i += 256) sb[i] = 0.f;
  for (int i = threadIdx.x; i < 512; i += 256) sc[i] = 0u;
  __syncthreads();
  for (int i = blockIdx.x * 256 + threadIdx.x; i < Nn; i += gridDim.x * 256) {
    int g = batch[i];
    float dv = dinv[i];
    float ns = dv * dv;
    float2 hv = *(const float2*)(H2 + 2 * (size_t)i);
    atomicAdd(&sb[2 * g],     ns * hv.x);
    atomicAdd(&sb[2 * g + 1], ns * hv.y);
    atomicAdd(&sc[g], 1u);
  }
  __syncthreads();
  for (int i = threadIdx.x; i < 1024; i += 256)
    if (sb[i] != 0.f) atomicAdd(&accg[i], sb[i]);
  for (int i = threadIdx.x; i < 512; i += 256)
    if (sc[i]) atomicAdd(&gcnt[i], sc[i]);
}

__global__ void k_final(const float* __restrict__ accg, const u32* __restrict__ gcnt,
                        const float* __restrict__ B2, float* __restrict__ out) {
  int i = blockIdx.x * 256 + threadIdx.x;
  if (i < 1024) {
    int g = i >> 1, c = i & 1;
    float cnt = (float)gcnt[g];
    float s = accg[i] + cnt * B2[c];
    out[i] = s / fmaxf(cnt, 1.0f);
  }
}

extern "C" void kernel_launch(void* const* d_in, const int* in_sizes, int n_in,
                              void* d_out, int out_size, void* d_ws, size_t ws_size,
                              hipStream_t stream) {
  const float* X     = (const float*)d_in[0];
  const int*   EI    = (const int*)d_in[1];
  const int*   BATCH = (const int*)d_in[2];
  const float* W1    = (const float*)d_in[3];
  const float* B1    = (const float*)d_in[4];
  const float* W2    = (const float*)d_in[5];
  const float* B2    = (const float*)d_in[6];
  const int Nn = in_sizes[0] / NF1;      // 100000
  const int E  = in_sizes[1] / 2;        // 1600000
  float* OUT = (float*)d_out;
  (void)n_in; (void)out_size; (void)ws_size;

  char* w = (char*)d_ws;
  size_t off = 0;
  auto alloc = [&](size_t bytes) -> void* {
    void* p = w + off;
    off = (off + bytes + 511) & ~(size_t)511;
    return p;
  };
  u32*   deg    = (u32*)alloc((size_t)Nn * 4);
  u32*   rowptr = (u32*)alloc(((size_t)Nn + 1) * 4);
  u32*   cursor = (u32*)alloc((size_t)Nn * 4);
  u32*   bsum   = (u32*)alloc(512);
  u32*   boff   = (u32*)alloc(512);
  float* dinv   = (float*)alloc((size_t)Nn * 4);
  int*   csr    = (int*)alloc((size_t)E * 4);
  u16*   H1     = (u16*)alloc((size_t)Nn * NF2 * 2);
  float* H2     = (float*)alloc((size_t)Nn * 2 * 4);
  float* accg   = (float*)alloc(1536 * 4);   // 1024 f32 sums + 512 u32 counts
  u32*   gcnt   = (u32*)(accg + 1024);
  u16*   W1T    = (u16*)alloc((size_t)NF1 * NF2 * 2);

  const int NC = (Nn + 1023) >> 10;          // scan chunks (98), must be <= 128

  hipLaunchKernelGGL(k_zero, dim3((Nn + 255) / 256), dim3(256), 0, stream, deg, Nn);
  hipLaunchKernelGGL(k_zero, dim3(6), dim3(256), 0, stream, (u32*)accg, 1536);
  hipLaunchKernelGGL(k_w1t, dim3((NF1 * NF2 + 255) / 256), dim3(256), 0, stream, W1, W1T);
  hipLaunchKernelGGL(k_gemm, dim3((Nn + 127) / 128, 2), dim3(256), 0, stream, X, W1T, H1, Nn);
  hipLaunchKernelGGL(k_deg, dim3((E + 255) / 256), dim3(256), 0, stream, EI, E, deg);
  hipLaunchKernelGGL(k_scan1, dim3(NC), dim3(1024), 0, stream, deg, rowptr, bsum, Nn);
  hipLaunchKernelGGL(k_scan2, dim3(1), dim3(128), 0, stream, bsum, boff, NC);
  hipLaunchKernelGGL(k_scan3, dim3((Nn + 255) / 256), dim3(256), 0, stream,
                     rowptr, boff, cursor, deg, dinv, Nn, E);
  hipLaunchKernelGGL(k_fill, dim3((E + 255) / 256), dim3(256), 0, stream,
                     EI, E, (int*)cursor, csr);
  hipLaunchKernelGGL(k_agg1, dim3((Nn + 3) / 4), dim3(256), 0, stream,
                     H1, csr, rowptr, dinv, B1, W2, H2, Nn);
  hipLaunchKernelGGL(k_l2e, dim3(512), dim3(256), 0, stream, EI, E, dinv, H2, BATCH, accg);
  hipLaunchKernelGGL(k_l2n, dim3(256), dim3(256), 0, stream, Nn, dinv, H2, BATCH, accg, gcnt);
  hipLaunchKernelGGL(k_final, dim3(4), dim3(256), 0, stream, accg, gcnt, B2, OUT);
}

// Round 8
// 490.258 us; speedup vs baseline: 1.4130x; 1.0217x over previous
//
#include <hip/hip_runtime.h>

typedef unsigned short u16;
typedef unsigned int   u32;
typedef __bf16 bf16x8 __attribute__((ext_vector_type(8)));
typedef float  f32x4  __attribute__((ext_vector_type(4)));
typedef u32    u32x4  __attribute__((ext_vector_type(4)));
typedef u16    u16x8  __attribute__((ext_vector_type(8)));

#define NF1 768   // input feature dim
#define NF2 256   // hidden feature dim

__device__ __forceinline__ u16 f2bf(float f) {
  u32 u = __builtin_bit_cast(u32, f);
  u += 0x7fffu + ((u >> 16) & 1u);      // RTNE
  return (u16)(u >> 16);
}
__device__ __forceinline__ float bf2f(u16 h) {
  return __builtin_bit_cast(float, ((u32)h) << 16);
}

// async global->LDS, 16B per lane. LDS dest is wave-uniform base + lane*16.
__device__ __forceinline__ void gll16(const void* g, void* l) {
  __builtin_amdgcn_global_load_lds(
      (const __attribute__((address_space(1))) unsigned int*)g,
      (__attribute__((address_space(3))) unsigned int*)l, 16, 0, 0);
}

// ---------------- utility ----------------
__global__ void k_zero(u32* __restrict__ p, int n) {
  int i = blockIdx.x * 256 + threadIdx.x;
  if (i < n) p[i] = 0u;
}

// W1 [768,256] f32 row-major -> W1T [256,768] bf16
__global__ void k_w1t(const float* __restrict__ W1, u16* __restrict__ W1T) {
  int idx = blockIdx.x * 256 + threadIdx.x;
  if (idx < NF1 * NF2) {
    int k = idx >> 8, j = idx & 255;
    W1T[(size_t)j * NF1 + k] = f2bf(W1[idx]);
  }
}

// ---------------- GEMM1: H1 = bf16(x @ W1), [M,256] bf16 ----------------
// R8: BN=256 full-width tile + double-buffered LDS (128KB, 1 block/CU) +
// counted vmcnt (T3/T4): each wave stages 16 global_load_lds per tile;
// iter t: s_waitcnt vmcnt(16) (tile t done, t+1 still in flight) -> raw
// s_barrier -> compute -> raw s_barrier -> stage tile t+2. Loads issued 2
// iterations ahead of use (~1600cy cover > ~900cy HBM latency). Never
// vmcnt(0) inside the loop. Raw barriers carry "memory" clobber +
// sched_barrier(0) (rule #18). Ledger is exact: no other VMEM in the loop.
__global__ __launch_bounds__(256, 1) void k_gemm(const float* __restrict__ X,
                                                 const u16* __restrict__ W1T,
                                                 u16* __restrict__ H1, int M) {
  __shared__ float lsA[2][128 * 64];   // 2 x 32 KB: byte = row*256 + unit*16
  __shared__ u16   lsB[2][256 * 64];   // 2 x 32 KB: byte = col*128 + unit*16
  const int t    = threadIdx.x;
  const int m0   = blockIdx.x * 128;
  const int lane = t & 63;
  const int wid  = t >> 6;
  const int wr   = wid >> 1, wc = wid & 1;   // wave tile: 64 rows x 128 cols

  // ---- staging source addresses (per-lane, pre-swizzled; rule #21) ----
  // A instr i (0..7): rows i*16 + wid*4 + (lane>>4); phys unit = lane&15.
  const int rowbase = wid * 4 + (lane >> 4);                       // 0..15
  const int perm_s  = ((rowbase & 7) << 1) | ((rowbase >> 3) & 1); // perm_a(row)
  const float* srcA[8];
  #pragma unroll
  for (int i = 0; i < 8; ++i) {
    int gr = m0 + i * 16 + rowbase;
    if (gr > M - 1) gr = M - 1;           // clamp (rows >= M computed, discarded)
    srcA[i] = X + (size_t)gr * NF1 + (((lane & 15) ^ perm_s) * 4);
  }
  // B instr j (0..7): cols j*32 + wid*8 + (lane>>3); phys unit = lane&7.
  const int colbase = wid * 8 + (lane >> 3);
  const u16* srcB[8];
  #pragma unroll
  for (int j = 0; j < 8; ++j) {
    int gc = j * 32 + colbase;
    srcB[j] = W1T + (size_t)gc * NF1 + (((lane & 7) ^ (lane >> 3)) * 8);
  }

#define STAGE(kt_, buf_) do {                                                  \
    _Pragma("unroll")                                                          \
    for (int i_ = 0; i_ < 8; ++i_)                                             \
      gll16(srcA[i_] + (kt_) * 64, &lsA[buf_][(i_ * 16 + wid * 4) * 64]);      \
    _Pragma("unroll")                                                          \
    for (int j_ = 0; j_ < 8; ++j_)                                             \
      gll16(srcB[j_] + (kt_) * 64, &lsB[buf_][(j_ * 32 + wid * 8) * 64]);      \
  } while (0)

  f32x4 acc[4][8];
  #pragma unroll
  for (int m = 0; m < 4; ++m)
    #pragma unroll
    for (int n = 0; n < 8; ++n) { f32x4 z = {0.f, 0.f, 0.f, 0.f}; acc[m][n] = z; }

  const int lm     = lane & 15;
  const int l4     = lane >> 4;
  const int perm_r = ((lane & 7) << 1) | ((lane >> 3) & 1);

  const int NT = NF1 / 64;   // 12
  STAGE(0, 0);               // 16 loads in flight
  STAGE(1, 1);               // 32 in flight

  #pragma unroll
  for (int kt = 0; kt < NT; ++kt) {
    if (kt < NT - 1) { asm volatile("s_waitcnt vmcnt(16)" ::: "memory"); }
    else             { asm volatile("s_waitcnt vmcnt(0)"  ::: "memory"); }
    __builtin_amdgcn_sched_barrier(0);
    asm volatile("s_barrier" ::: "memory");     // tile kt ready (all waves)
    __builtin_amdgcn_sched_barrier(0);

    const float* curA = lsA[kt & 1];
    const u16*   curB = lsB[kt & 1];
    #pragma unroll
    for (int ks = 0; ks < 2; ++ks) {
      bf16x8 af[4], bfr[8];
      #pragma unroll
      for (int m = 0; m < 4; ++m) {
        int row  = wr * 64 + m * 16 + lm;
        int c    = ks * 4 + l4;
        int ulo  = (2 * c) ^ perm_r;
        const char* base = (const char*)curA + row * 256;
        float4 L = *(const float4*)(base + ulo * 16);
        float4 H = *(const float4*)(base + (ulo ^ 1) * 16);
        u32 w0, w1, w2, w3;
        asm("v_cvt_pk_bf16_f32 %0, %1, %2" : "=v"(w0) : "v"(L.x), "v"(L.y));
        asm("v_cvt_pk_bf16_f32 %0, %1, %2" : "=v"(w1) : "v"(L.z), "v"(L.w));
        asm("v_cvt_pk_bf16_f32 %0, %1, %2" : "=v"(w2) : "v"(H.x), "v"(H.y));
        asm("v_cvt_pk_bf16_f32 %0, %1, %2" : "=v"(w3) : "v"(H.z), "v"(H.w));
        u32x4 uw = {w0, w1, w2, w3};
        af[m] = __builtin_bit_cast(bf16x8, uw);
      }
      #pragma unroll
      for (int n = 0; n < 8; ++n) {
        int col = wc * 128 + n * 16 + lm;
        int u   = ks * 4 + l4;
        int ph  = u ^ (lane & 7);               // perm_b(col) = col&7 = lane&7
        bfr[n] = *(const bf16x8*)((const char*)curB + col * 128 + ph * 16);
      }
      #pragma unroll
      for (int m = 0; m < 4; ++m)
        #pragma unroll
        for (int n = 0; n < 8; ++n)
          acc[m][n] = __builtin_amdgcn_mfma_f32_16x16x32_bf16(af[m], bfr[n], acc[m][n], 0, 0, 0);
    }

    __builtin_amdgcn_sched_barrier(0);
    asm volatile("s_barrier" ::: "memory");     // all waves done reading buf
    if (kt + 2 < NT) STAGE(kt + 2, kt & 1);     // refill consumed buffer
  }
#undef STAGE

  // epilogue: D col=lane&15, row=(lane>>4)*4+j  (m89-verified layout)
  #pragma unroll
  for (int m = 0; m < 4; ++m) {
    int rowb = m0 + wr * 64 + m * 16 + (lane >> 4) * 4;
    #pragma unroll
    for (int n = 0; n < 8; ++n) {
      int col = wc * 128 + n * 16 + (lane & 15);
      #pragma unroll
      for (int j = 0; j < 4; ++j) {
        int row = rowb + j;
        if (row < M) H1[(size_t)row * NF2 + col] = f2bf(acc[m][n][j]);
      }
    }
  }
}

// ---------------- degree / CSR build ----------------
__global__ void k_deg(const int* __restrict__ EI, int E, u32* __restrict__ deg) {
  int e = blockIdx.x * 256 + threadIdx.x;
  if (e < E) atomicAdd(&deg[EI[E + e]], 1u);
}

__global__ __launch_bounds__(1024) void k_scan1(const u32* __restrict__ deg,
                                                u32* __restrict__ rowptr,
                                                u32* __restrict__ bsum, int Nn) {
  __shared__ u32 sm[1024];
  int t = threadIdx.x;
  int i = blockIdx.x * 1024 + t;
  u32 v = (i < Nn) ? deg[i] : 0u;
  sm[t] = v;
  __syncthreads();
  #pragma unroll
  for (int off = 1; off < 1024; off <<= 1) {
    u32 x = (t >= off) ? sm[t - off] : 0u;
    __syncthreads();
    sm[t] += x;
    __syncthreads();
  }
  u32 incl = sm[t];
  if (i < Nn) rowptr[i] = incl - v;
  if (t == 1023) bsum[blockIdx.x] = incl;
}

__global__ void k_scan2(const u32* __restrict__ bsum, u32* __restrict__ boff, int nc) {
  __shared__ u32 sm[128];
  int t = threadIdx.x;
  u32 v = (t < nc) ? bsum[t] : 0u;
  sm[t] = v;
  __syncthreads();
  #pragma unroll
  for (int off = 1; off < 128; off <<= 1) {
    u32 x = (t >= off) ? sm[t - off] : 0u;
    __syncthreads();
    sm[t] += x;
    __syncthreads();
  }
  if (t < nc) boff[t] = sm[t] - v;
}

__global__ void k_scan3(u32* __restrict__ rowptr, const u32* __restrict__ boff,
                        u32* __restrict__ cursor, const u32* __restrict__ deg,
                        float* __restrict__ dinv, int Nn, int E) {
  int i = blockIdx.x * 256 + threadIdx.x;
  if (i < Nn) {
    u32 rp = rowptr[i] + boff[i >> 10];
    rowptr[i] = rp;
    cursor[i] = rp;
    dinv[i] = rsqrtf((float)deg[i] + 1.0f);
  }
  if (i == 0) rowptr[Nn] = (u32)E;
}

__global__ void k_fill(const int* __restrict__ EI, int E, int* __restrict__ cursor,
                       int* __restrict__ csr) {
  int e = blockIdx.x * 256 + threadIdx.x;
  if (e < E) {
    int s = EI[e], d = EI[E + e];
    int pos = atomicAdd(&cursor[d], 1);
    csr[pos] = s;
  }
}

// ---------------- fused: agg1 + self + b1 + relu + @W2 -> H2 [N,2] ----------------
// R7 structure (validated): split-wave gather, 4 edges in flight per half-wave.
__global__ __launch_bounds__(256) void k_agg1(const u16* __restrict__ H1,
                                              const int* __restrict__ csr,
                                              const u32* __restrict__ rowptr,
                                              const float* __restrict__ dinv,
                                              const float* __restrict__ B1,
                                              const float* __restrict__ W2,
                                              float* __restrict__ H2, int Nn) {
  int node = (blockIdx.x << 2) + (threadIdx.x >> 6);
  if (node >= Nn) return;
  const int lane = threadIdx.x & 63;
  const int hl   = lane >> 5;        // half-wave 0/1
  const int fo   = (lane & 31) * 8;  // feature offset (8 bf16 = 16B per lane)
  const int rp0 = (int)rowptr[node], rp1 = (int)rowptr[node + 1];
  const float dvi = dinv[node];

  float c0 = 0.f, c1 = 0.f, c2 = 0.f, c3 = 0.f,
        c4 = 0.f, c5 = 0.f, c6 = 0.f, c7 = 0.f;

  for (int e = rp0 + 2 * hl; e < rp1; e += 8) {
    const int eA = e, eB = e + 1, eC = e + 4, eD = e + 5;
    const bool hB = eB < rp1, hC = eC < rp1, hD = eD < rp1;
    const int sA = csr[eA];
    const int sB = hB ? csr[eB] : sA;
    const int sC = hC ? csr[eC] : sA;
    const int sD = hD ? csr[eD] : sA;
    const u16x8 rA = *(const u16x8*)(H1 + (size_t)sA * NF2 + fo);
    const u16x8 rB = *(const u16x8*)(H1 + (size_t)sB * NF2 + fo);
    const u16x8 rC = *(const u16x8*)(H1 + (size_t)sC * NF2 + fo);
    const u16x8 rD = *(const u16x8*)(H1 + (size_t)sD * NF2 + fo);
    const float nA = dinv[sA] * dvi;
    const float nB = hB ? dinv[sB] * dvi : 0.f;
    const float nC = hC ? dinv[sC] * dvi : 0.f;
    const float nD = hD ? dinv[sD] * dvi : 0.f;
    c0 += nA * bf2f(rA[0]) + nB * bf2f(rB[0]) + nC * bf2f(rC[0]) + nD * bf2f(rD[0]);
    c1 += nA * bf2f(rA[1]) + nB * bf2f(rB[1]) + nC * bf2f(rC[1]) + nD * bf2f(rD[1]);
    c2 += nA * bf2f(rA[2]) + nB * bf2f(rB[2]) + nC * bf2f(rC[2]) + nD * bf2f(rD[2]);
    c3 += nA * bf2f(rA[3]) + nB * bf2f(rB[3]) + nC * bf2f(rC[3]) + nD * bf2f(rD[3]);
    c4 += nA * bf2f(rA[4]) + nB * bf2f(rB[4]) + nC * bf2f(rC[4]) + nD * bf2f(rD[4]);
    c5 += nA * bf2f(rA[5]) + nB * bf2f(rB[5]) + nC * bf2f(rC[5]) + nD * bf2f(rD[5]);
    c6 += nA * bf2f(rA[6]) + nB * bf2f(rB[6]) + nC * bf2f(rC[6]) + nD * bf2f(rD[6]);
    c7 += nA * bf2f(rA[7]) + nB * bf2f(rB[7]) + nC * bf2f(rC[7]) + nD * bf2f(rD[7]);
  }

  c0 += __shfl_xor(c0, 32);
  c1 += __shfl_xor(c1, 32);
  c2 += __shfl_xor(c2, 32);
  c3 += __shfl_xor(c3, 32);
  c4 += __shfl_xor(c4, 32);
  c5 += __shfl_xor(c5, 32);
  c6 += __shfl_xor(c6, 32);
  c7 += __shfl_xor(c7, 32);

  {   // self-loop: norm = dinv^2 = 1/deg
    const float ns = dvi * dvi;
    const u16x8 rs = *(const u16x8*)(H1 + (size_t)node * NF2 + fo);
    c0 += ns * bf2f(rs[0]); c1 += ns * bf2f(rs[1]);
    c2 += ns * bf2f(rs[2]); c3 += ns * bf2f(rs[3]);
    c4 += ns * bf2f(rs[4]); c5 += ns * bf2f(rs[5]);
    c6 += ns * bf2f(rs[6]); c7 += ns * bf2f(rs[7]);
  }

  const float4 bA = *(const float4*)(B1 + fo);
  const float4 bB = *(const float4*)(B1 + fo + 4);
  const float r0 = fmaxf(c0 + bA.x, 0.f), r1 = fmaxf(c1 + bA.y, 0.f);
  const float r2 = fmaxf(c2 + bA.z, 0.f), r3 = fmaxf(c3 + bA.w, 0.f);
  const float r4 = fmaxf(c4 + bB.x, 0.f), r5 = fmaxf(c5 + bB.y, 0.f);
  const float r6 = fmaxf(c6 + bB.z, 0.f), r7 = fmaxf(c7 + bB.w, 0.f);

  const float4* wp = (const float4*)(W2 + 2 * fo);   // W2[fo..fo+7][0..1]
  const float4 w0 = wp[0], w1 = wp[1], w2 = wp[2], w3 = wp[3];
  float p0 = r0 * w0.x + r1 * w0.z + r2 * w1.x + r3 * w1.z
           + r4 * w2.x + r5 * w2.z + r6 * w3.x + r7 * w3.z;
  float p1 = r0 * w0.y + r1 * w0.w + r2 * w1.y + r3 * w1.w
           + r4 * w2.y + r5 * w2.w + r6 * w3.y + r7 * w3.w;
  #pragma unroll
  for (int o = 16; o; o >>= 1) {
    p0 += __shfl_xor(p0, o);
    p1 += __shfl_xor(p1, o);
  }
  if (lane == 0) {
    H2[2 * (size_t)node]     = p0;
    H2[2 * (size_t)node + 1] = p1;
  }
}

// ---------------- layer-2 edge aggregation, pooled directly into graph bins ----------------
__global__ __launch_bounds__(256) void k_l2e(const int* __restrict__ EI, int E,
                                             const float* __restrict__ dinv,
                                             const float* __restrict__ H2,
                                             const int* __restrict__ batch,
                                             float* __restrict__ accg) {
  __shared__ float sb[1024];
  for (int i = threadIdx.x; i < 1024; i += 256) sb[i] = 0.f;
  __syncthreads();
  for (int e = blockIdx.x * 256 + threadIdx.x; e < E; e += gridDim.x * 256) {
    int s = EI[e], d = EI[E + e];
    float nrm = dinv[s] * dinv[d];
    float2 hv = *(const float2*)(H2 + 2 * (size_t)s);
    int g = batch[d];
    atomicAdd(&sb[2 * g],     nrm * hv.x);
    atomicAdd(&sb[2 * g + 1], nrm * hv.y);
  }
  __syncthreads();
  for (int i = threadIdx.x; i < 1024; i += 256)
    if (sb[i] != 0.f) atomicAdd(&accg[i], sb[i]);
}

// layer-2 self-loop + per-graph counts
__global__ __launch_bounds__(256) void k_l2n(int Nn, const float* __restrict__ dinv,
                                             const float* __restrict__ H2,
                                             const int* __restrict__ batch,
                                             float* __restrict__ accg,
                                             u32* __restrict__ gcnt) {
  __shared__ float sb[1024];
  __shared__ u32 sc[512];
  for (int i = threadIdx.x; i < 1024; i += 256) sb[i] = 0.f;
  for (int i = threadIdx.x; i < 512; i += 256) sc[i] = 0u;
  __syncthreads();
  for (int i = blockIdx.x * 256 + threadIdx.x; i < Nn; i += gridDim.x * 256) {
    int g = batch[i];
    float dv = dinv[i];
    float ns = dv * dv;
    float2 hv = *(const float2*)(H2 + 2 * (size_t)i);
    atomicAdd(&sb[2 * g],     ns * hv.x);
    atomicAdd(&sb[2 * g + 1], ns * hv.y);
    atomicAdd(&sc[g], 1u);
  }
  __syncthreads();
  for (int i = threadIdx.x; i < 1024; i += 256)
    if (sb[i] != 0.f) atomicAdd(&accg[i], sb[i]);
  for (int i = threadIdx.x; i < 512; i += 256)
    if (sc[i]) atomicAdd(&gcnt[i], sc[i]);
}

__global__ void k_final(const float* __restrict__ accg, const u32* __restrict__ gcnt,
                        const float* __restrict__ B2, float* __restrict__ out) {
  int i = blockIdx.x * 256 + threadIdx.x;
  if (i < 1024) {
    int g = i >> 1, c = i & 1;
    float cnt = (float)gcnt[g];
    float s = accg[i] + cnt * B2[c];
    out[i] = s / fmaxf(cnt, 1.0f);
  }
}

extern "C" void kernel_launch(void* const* d_in, const int* in_sizes, int n_in,
                              void* d_out, int out_size, void* d_ws, size_t ws_size,
                              hipStream_t stream) {
  const float* X     = (const float*)d_in[0];
  const int*   EI    = (const int*)d_in[1];
  const int*   BATCH = (const int*)d_in[2];
  const float* W1    = (const float*)d_in[3];
  const float* B1    = (const float*)d_in[4];
  const float* W2    = (const float*)d_in[5];
  const float* B2    = (const float*)d_in[6];
  const int Nn = in_sizes[0] / NF1;      // 100000
  const int E  = in_sizes[1] / 2;        // 1600000
  float* OUT = (float*)d_out;
  (void)n_in; (void)out_size; (void)ws_size;

  char* w = (char*)d_ws;
  size_t off = 0;
  auto alloc = [&](size_t bytes) -> void* {
    void* p = w + off;
    off = (off + bytes + 511) & ~(size_t)511;
    return p;
  };
  u32*   deg    = (u32*)alloc((size_t)Nn * 4);
  u32*   rowptr = (u32*)alloc(((size_t)Nn + 1) * 4);
  u32*   cursor = (u32*)alloc((size_t)Nn * 4);
  u32*   bsum   = (u32*)alloc(512);
  u32*   boff   = (u32*)alloc(512);
  float* dinv   = (float*)alloc((size_t)Nn * 4);
  int*   csr    = (int*)alloc((size_t)E * 4);
  u16*   H1     = (u16*)alloc((size_t)Nn * NF2 * 2);
  float* H2     = (float*)alloc((size_t)Nn * 2 * 4);
  float* accg   = (float*)alloc(1536 * 4);   // 1024 f32 sums + 512 u32 counts
  u32*   gcnt   = (u32*)(accg + 1024);
  u16*   W1T    = (u16*)alloc((size_t)NF1 * NF2 * 2);

  const int NC = (Nn + 1023) >> 10;          // scan chunks (98), must be <= 128

  hipLaunchKernelGGL(k_zero, dim3((Nn + 255) / 256), dim3(256), 0, stream, deg, Nn);
  hipLaunchKernelGGL(k_zero, dim3(6), dim3(256), 0, stream, (u32*)accg, 1536);
  hipLaunchKernelGGL(k_w1t, dim3((NF1 * NF2 + 255) / 256), dim3(256), 0, stream, W1, W1T);
  hipLaunchKernelGGL(k_gemm, dim3((Nn + 127) / 128), dim3(256), 0, stream, X, W1T, H1, Nn);
  hipLaunchKernelGGL(k_deg, dim3((E + 255) / 256), dim3(256), 0, stream, EI, E, deg);
  hipLaunchKernelGGL(k_scan1, dim3(NC), dim3(1024), 0, stream, deg, rowptr, bsum, Nn);
  hipLaunchKernelGGL(k_scan2, dim3(1), dim3(128), 0, stream, bsum, boff, NC);
  hipLaunchKernelGGL(k_scan3, dim3((Nn + 255) / 256), dim3(256), 0, stream,
                     rowptr, boff, cursor, deg, dinv, Nn, E);
  hipLaunchKernelGGL(k_fill, dim3((E + 255) / 256), dim3(256), 0, stream,
                     EI, E, (int*)cursor, csr);
  hipLaunchKernelGGL(k_agg1, dim3((Nn + 3) / 4), dim3(256), 0, stream,
                     H1, csr, rowptr, dinv, B1, W2, H2, Nn);
  hipLaunchKernelGGL(k_l2e, dim3(512), dim3(256), 0, stream, EI, E, dinv, H2, BATCH, accg);
  hipLaunchKernelGGL(k_l2n, dim3(256), dim3(256), 0, stream, Nn, dinv, H2, BATCH, accg, gcnt);
  hipLaunchKernelGGL(k_final, dim3(4), dim3(256), 0, stream, accg, gcnt, B2, OUT);
}